// Round 7
// baseline (1005.446 us; speedup 1.0000x reference)
//
#include <hip/hip_runtime.h>
#include <hip/hip_bf16.h>
#include <math.h>

typedef __hip_bfloat16 bf16;
typedef __attribute__((ext_vector_type(8))) short short8v;   // 8 x bf16 frag
typedef __attribute__((ext_vector_type(4))) float f32x4;

static constexpr float EPS_   = 1e-6f;
static constexpr float NEG_   = -1000000000.0f;
static constexpr float SCALE_ = 0.13523378f;        // (0.1*ln40+1)^2 / sqrt(192)
static constexpr float IDXSC_ = 0.08838834764832f;  // 1/sqrt(128)
static constexpr double LN10K_32 = 0.28782313662425575; // ln(10000)/32

#define MFMA16(a, b, c) __builtin_amdgcn_mfma_f32_16x16x32_bf16(a, b, c, 0, 0, 0)

// async global->LDS 16B (HW DMA, no VGPR round-trip)
__device__ __forceinline__ void gld16(const void* g, void* l) {
  __builtin_amdgcn_global_load_lds(
      (const __attribute__((address_space(1))) void*)g,
      (__attribute__((address_space(3))) void*)l, 16, 0, 0);
}

// ---------------- block reduce (sum op=0, max op=1) ----------------
static __device__ float block_reduce_op(float v, int op) {
  __shared__ float red_s[16];
  int lane = threadIdx.x & 63, wid = threadIdx.x >> 6;
  #pragma unroll
  for (int off = 32; off > 0; off >>= 1) {
    float o = __shfl_down(v, off);
    v = op ? fmaxf(v, o) : (v + o);
  }
  __syncthreads();
  if (lane == 0) red_s[wid] = v;
  __syncthreads();
  if (threadIdx.x == 0) {
    int nw = ((int)blockDim.x + 63) >> 6;
    float r = red_s[0];
    for (int i = 1; i < nw; i++) r = op ? fmaxf(r, red_s[i]) : (r + red_s[i]);
    red_s[0] = r;
  }
  __syncthreads();
  return red_s[0];
}

// ---------------- f32 -> bf16 ----------------
__global__ __launch_bounds__(256) void f2b_kernel(const float* __restrict__ in,
                                                  bf16* __restrict__ out, long n) {
  long i = ((long)blockIdx.x * 256 + threadIdx.x) * 4;
  if (i + 3 < n) {
    float4 v = *(const float4*)(in + i);
    out[i] = __float2bfloat16(v.x); out[i+1] = __float2bfloat16(v.y);
    out[i+2] = __float2bfloat16(v.z); out[i+3] = __float2bfloat16(v.w);
  } else {
    for (int j = 0; j < 4 && i + j < n; j++) out[i+j] = __float2bfloat16(in[i+j]);
  }
}

// ---------------- bf16 MFMA GEMM (global_load_lds staging, linear LDS) ----------
// BT=1: C[m,n] = sum_k A[m,k]*B[n,k];  BT=0: C[m,n] = sum_k A[m,k]*B[k,n]
// tiles 128x128, BK=32, 256 threads. M%128==0, K%32==0. OB=1 -> bf16 out.
template <int BT, int OB>
__global__ __launch_bounds__(256) void gemm_bf16(
    const bf16* __restrict__ A, const bf16* __restrict__ B, void* __restrict__ Cv,
    int M, int N, int K, int lda, int ldb, int ldc, long sA, long sB, long sC) {
  A += (long)blockIdx.z * sA;
  B += (long)blockIdx.z * sB;
  __shared__ bf16 As[4096];   // [128 rows][32 k] linear
  __shared__ bf16 Bs[4096];
  const int m0 = blockIdx.y * 128, n0 = blockIdx.x * 128;
  const int tid = threadIdx.x;
  const int wave = tid >> 6, lane = tid & 63, g = lane >> 4, li = lane & 15;
  const int mB = (wave >> 1) * 64, nB = (wave & 1) * 64;
  f32x4 acc[4][4];
  #pragma unroll
  for (int i = 0; i < 4; i++)
    #pragma unroll
    for (int j = 0; j < 4; j++) acc[i][j] = (f32x4){0.f, 0.f, 0.f, 0.f};

  for (int k0 = 0; k0 < K; k0 += 32) {
    #pragma unroll
    for (int r2 = 0; r2 < 2; r2++) {
      int idx = r2 * 256 + tid;
      int row = idx >> 2, ko = (idx & 3) * 8;
      gld16(A + (long)(m0 + row) * lda + k0 + ko, &As[idx * 8]);
    }
    if (BT) {
      #pragma unroll
      for (int r2 = 0; r2 < 2; r2++) {
        int idx = r2 * 256 + tid;
        int row = idx >> 2, ko = (idx & 3) * 8;
        int rr = n0 + row; if (rr >= N) rr = N - 1;
        gld16(B + (long)rr * ldb + k0 + ko, &Bs[idx * 8]);
      }
    } else {
      int k = tid >> 3, nb = (tid & 7) * 16;
      const bf16* src = B + (long)(k0 + k) * ldb + n0 + nb;
      short8v v0 = *(const short8v*)src;
      short8v v1 = *(const short8v*)(src + 8);
      #pragma unroll
      for (int j = 0; j < 8; j++) {
        Bs[(nb + j) * 32 + k]     = ((const bf16*)&v0)[j];
        Bs[(nb + 8 + j) * 32 + k] = ((const bf16*)&v1)[j];
      }
    }
    __syncthreads();
    short8v af[4], bfr[4];
    #pragma unroll
    for (int mt = 0; mt < 4; mt++) af[mt]  = *(const short8v*)&As[(mB + mt*16 + li) * 32 + g*8];
    #pragma unroll
    for (int nt = 0; nt < 4; nt++) bfr[nt] = *(const short8v*)&Bs[(nB + nt*16 + li) * 32 + g*8];
    #pragma unroll
    for (int mt = 0; mt < 4; mt++)
      #pragma unroll
      for (int nt = 0; nt < 4; nt++)
        acc[mt][nt] = MFMA16(af[mt], bfr[nt], acc[mt][nt]);
    __syncthreads();
  }
  #pragma unroll
  for (int mt = 0; mt < 4; mt++)
    #pragma unroll
    for (int nt = 0; nt < 4; nt++)
      #pragma unroll
      for (int r = 0; r < 4; r++) {
        int row = m0 + mB + mt*16 + g*4 + r;
        int col = n0 + nB + nt*16 + li;
        if (col < N) {
          long off = (long)blockIdx.z * sC + (long)row * ldc + col;
          if (OB) ((bf16*)Cv)[off] = __float2bfloat16(acc[mt][nt][r]);
          else    ((float*)Cv)[off] = acc[mt][nt][r];
        }
      }
}

// ---------------- rmsnorm (f32 in -> bf16 out) ----------------
__global__ __launch_bounds__(256) void rmsnorm_b_kernel(const float* __restrict__ x,
                                                        const float* __restrict__ w,
                                                        bf16* __restrict__ out, int D) {
  const float* r = x + (long)blockIdx.x * D;
  bf16* o = out + (long)blockIdx.x * D;
  float ss = 0.f;
  for (int i = threadIdx.x; i < D; i += 256) { float v = r[i]; ss = fmaf(v, v, ss); }
  ss = block_reduce_op(ss, 0);
  float sc = rsqrtf(ss / (float)D + EPS_);
  for (int i = threadIdx.x; i < D; i += 256) o[i] = __float2bfloat16(r[i] * sc * w[i]);
}

// ---------------- kv row: rmsnorm 512 + rope 64 -> keys_b[s][576] ----------------
__global__ __launch_bounds__(256) void kv_norm_rope_kernel(const float* __restrict__ kv,
                                                           const float* __restrict__ w,
                                                           bf16* __restrict__ keys_b) {
  int s = blockIdx.x;
  const float* r = kv + (long)s * 576;
  float ss = 0.f;
  for (int i = threadIdx.x; i < 512; i += 256) { float v = r[i]; ss = fmaf(v, v, ss); }
  ss = block_reduce_op(ss, 0);
  float sc = rsqrtf(ss / 512.f + EPS_);
  for (int i = threadIdx.x; i < 512; i += 256)
    keys_b[(long)s * 576 + i] = __float2bfloat16(r[i] * sc * w[i]);
  if (threadIdx.x < 32) {
    int j = threadIdx.x;
    float f = (float)exp(-(double)j * LN10K_32);
    float ang = (float)s * f;
    float c = cosf(ang), sn = sinf(ang);
    float x1 = r[512 + 2*j], x2 = r[512 + 2*j + 1];
    keys_b[(long)s * 576 + 512 + 2*j]     = __float2bfloat16(x1 * c - x2 * sn);
    keys_b[(long)s * 576 + 512 + 2*j + 1] = __float2bfloat16(x1 * sn + x2 * c);
  }
}

// ---------------- main-q rope (bf16 -> qabs_b pe region) ----------------
__global__ __launch_bounds__(256) void rope_q_kernel(const bf16* __restrict__ q,
                                                     bf16* __restrict__ qabs) {
  int idx = blockIdx.x * 256 + threadIdx.x;  // (s*16+h)*32+j
  int j = idx & 31, h = (idx >> 5) & 15, s = idx >> 9;
  float f = (float)exp(-(double)j * LN10K_32);
  float ang = (float)s * f;
  float c = cosf(ang), sn = sinf(ang);
  const bf16* src = q + (long)s * 3072 + h * 192 + 128;
  float x1 = __bfloat162float(src[2*j]), x2 = __bfloat162float(src[2*j+1]);
  bf16* dst = qabs + (long)s * 9216 + h * 576 + 512;
  dst[2*j]     = __float2bfloat16(x1 * c - x2 * sn);
  dst[2*j + 1] = __float2bfloat16(x1 * sn + x2 * c);
}

// ---------------- indexer-q half rope in place (bf16) ----------------
__global__ __launch_bounds__(256) void rope_qi_kernel(bf16* __restrict__ qi) {
  int idx = blockIdx.x * 256 + threadIdx.x;  // (s*4+ih)*32+j
  int j = idx & 31, ih = (idx >> 5) & 3, s = idx >> 7;
  float f = (float)exp(-(double)j * LN10K_32);
  float ang = (float)s * f;
  float c = cosf(ang), sn = sinf(ang);
  bf16* p = qi + (long)s * 512 + ih * 128;
  float x1 = __bfloat162float(p[j]), x2 = __bfloat162float(p[32 + j]);
  p[j]      = __float2bfloat16(x1 * c - x2 * sn);
  p[32 + j] = __float2bfloat16(x1 * sn + x2 * c);
}

// ---------------- indexer-k: layernorm + half rope -> ki_b[s][128] ----------------
__global__ __launch_bounds__(128) void ki_ln_rope_kernel(const float* __restrict__ kt,
                                                         const float* __restrict__ w,
                                                         const float* __restrict__ b,
                                                         bf16* __restrict__ ki_b) {
  int s = blockIdx.x, d = threadIdx.x;
  float v = kt[(long)s * 128 + d];
  float m = block_reduce_op(v, 0) * (1.f / 128.f);
  float dv = v - m;
  float var = block_reduce_op(dv * dv, 0) * (1.f / 128.f);
  float y = dv * rsqrtf(var + EPS_) * w[d] + b[d];
  __shared__ float ys[128];
  ys[d] = y;
  __syncthreads();
  float out;
  if (d < 64) {
    int j = d & 31;
    float f = (float)exp(-(double)j * LN10K_32);
    float ang = (float)s * f;
    float c = cosf(ang), sn = sinf(ang);
    float x1 = ys[j], x2 = ys[32 + j];
    out = (d < 32) ? (x1 * c - x2 * sn) : (x1 * sn + x2 * c);
  } else out = y;
  ki_b[(long)s * 128 + d] = __float2bfloat16(out);
}

// ---------------- gate weights: x @ idx_ww.T * 0.5 (f32) ----------------
__global__ __launch_bounds__(256) void wgt_kernel(const float* __restrict__ x,
                                                  const float* __restrict__ ww,
                                                  float* __restrict__ wgt) {
  int s = blockIdx.x;
  float a0 = 0, a1 = 0, a2 = 0, a3 = 0;
  for (int i = threadIdx.x; i < 2048; i += 256) {
    float xv = x[(long)s * 2048 + i];
    a0 = fmaf(xv, ww[i], a0);
    a1 = fmaf(xv, ww[2048 + i], a1);
    a2 = fmaf(xv, ww[4096 + i], a2);
    a3 = fmaf(xv, ww[6144 + i], a3);
  }
  a0 = block_reduce_op(a0, 0);
  a1 = block_reduce_op(a1, 0);
  a2 = block_reduce_op(a2, 0);
  a3 = block_reduce_op(a3, 0);
  if (threadIdx.x == 0) {
    wgt[s*4+0] = 0.5f*a0; wgt[s*4+1] = 0.5f*a1; wgt[s*4+2] = 0.5f*a2; wgt[s*4+3] = 0.5f*a3;
  }
}

// ---------------- indexer logits via MFMA: tile 64t x 128s ----------------
__global__ __launch_bounds__(256) void idx_logits_mfma(const bf16* __restrict__ qi,
                                                       const bf16* __restrict__ ki,
                                                       const float* __restrict__ wgt,
                                                       float* __restrict__ logits) {
  const int t0 = blockIdx.y * 64, s0 = blockIdx.x * 128;
  const int tid = threadIdx.x, wave = tid >> 6, lane = tid & 63;
  const int g = lane >> 4, li = lane & 15;
  if (s0 > t0 + 63) {  // fully causal-masked tile
    #pragma unroll
    for (int j = 0; j < 8; j++)
      #pragma unroll
      for (int r = 0; r < 4; r++) {
        int t = t0 + wave*16 + g*4 + r, sidx = s0 + j*16 + li;
        logits[(long)t * 2048 + sidx] = NEG_;
      }
    return;
  }
  f32x4 acc[8];
  #pragma unroll
  for (int j = 0; j < 8; j++) acc[j] = (f32x4){0.f,0.f,0.f,0.f};
  #pragma unroll
  for (int h = 0; h < 4; h++) {
    f32x4 tmp[8];
    #pragma unroll
    for (int j = 0; j < 8; j++) tmp[j] = (f32x4){0.f,0.f,0.f,0.f};
    const bf16* arow = qi + ((long)(t0 + wave*16 + li) * 4 + h) * 128 + g*8;
    #pragma unroll
    for (int ks = 0; ks < 4; ks++) {
      short8v a = *(const short8v*)(arow + ks*32);
      #pragma unroll
      for (int j = 0; j < 8; j++) {
        const bf16* brow = ki + (long)(s0 + j*16 + li) * 128 + ks*32 + g*8;
        tmp[j] = MFMA16(a, *(const short8v*)brow, tmp[j]);
      }
    }
    #pragma unroll
    for (int r = 0; r < 4; r++) {
      float wv = wgt[(t0 + wave*16 + g*4 + r)*4 + h];
      #pragma unroll
      for (int j = 0; j < 8; j++)
        acc[j][r] += fmaxf(tmp[j][r] * IDXSC_, 0.f) * wv;
    }
  }
  #pragma unroll
  for (int j = 0; j < 8; j++)
    #pragma unroll
    for (int r = 0; r < 4; r++) {
      int t = t0 + wave*16 + g*4 + r, sidx = s0 + j*16 + li;
      logits[(long)t * 2048 + sidx] = acc[j][r] + (sidx <= t ? 0.f : NEG_);
    }
}

// ---------------- per-row top-512 (set semantics) ----------------
__global__ __launch_bounds__(256) void topk_kernel(const float* __restrict__ logits,
                                                   int* __restrict__ tki,
                                                   float* __restrict__ tkv,
                                                   float* __restrict__ logZ) {
  int t = blockIdx.x;
  __shared__ unsigned skeys[2048];
  __shared__ unsigned hist[256];
  __shared__ float svals[512];
  __shared__ int s_want;
  __shared__ unsigned s_prefix;
  const float* row = logits + (long)t * 2048;
  for (int i = threadIdx.x; i < 2048; i += 256) {
    unsigned u = __float_as_uint(row[i]);
    skeys[i] = (u & 0x80000000u) ? ~u : (u | 0x80000000u);
  }
  if (threadIdx.x == 0) { s_want = 512; s_prefix = 0u; }
  __syncthreads();
  for (int shift = 24; shift >= 0; shift -= 8) {
    if (threadIdx.x < 256) hist[threadIdx.x] = 0u;
    __syncthreads();
    unsigned pmask = (shift == 24) ? 0u : (0xFFFFFFFFu << (shift + 8));
    unsigned pref = s_prefix;
    for (int i = threadIdx.x; i < 2048; i += 256) {
      unsigned k = skeys[i];
      if ((k & pmask) == pref) atomicAdd(&hist[(k >> shift) & 255u], 1u);
    }
    __syncthreads();
    if (threadIdx.x == 0) {
      int want = s_want;
      unsigned cum = 0;
      int b = 255;
      for (;; b--) {
        cum += hist[b];
        if ((int)cum >= want || b == 0) break;
      }
      s_want = want - (int)(cum - hist[b]);
      s_prefix = pref | ((unsigned)b << shift);
    }
    __syncthreads();
  }
  unsigned T = s_prefix;
  int want_eq = s_want;
  int c_gt = 512 - want_eq;
  if (threadIdx.x < 64) {
    int n_gt = 0, n_eq = 0;
    unsigned long long below = (1ull << threadIdx.x) - 1ull;
    for (int base = 0; base < 2048; base += 64) {
      int i = base + (int)threadIdx.x;
      unsigned k = skeys[i];
      bool gt = (k > T), eq = (k == T);
      unsigned long long bg = __ballot(gt);
      unsigned long long be = __ballot(eq);
      int slot = -1;
      if (gt) slot = n_gt + (int)__popcll(bg & below);
      else if (eq) {
        int er = n_eq + (int)__popcll(be & below);
        if (er < want_eq) slot = c_gt + er;
      }
      if (slot >= 0) {
        unsigned bits = (k & 0x80000000u) ? (k ^ 0x80000000u) : ~k;
        float val = __uint_as_float(bits);
        tki[(long)t * 512 + slot] = i;
        tkv[(long)t * 512 + slot] = val;
        svals[slot] = val;
      }
      n_gt += (int)__popcll(bg);
      n_eq += (int)__popcll(be);
    }
  }
  __syncthreads();
  float m = -3.4e38f;
  for (int i = threadIdx.x; i < 512; i += 256) m = fmaxf(m, svals[i]);
  m = block_reduce_op(m, 1);
  float se = 0.f;
  for (int i = threadIdx.x; i < 512; i += 256) se += expf(svals[i] - m);
  se = block_reduce_op(se, 0);
  if (threadIdx.x == 0) logZ[t] = m + logf(se);
}

// ---------------- attn phase 1: QK^T + softmax + KL + dense-P emit ----------------
// 1 query/block, 4 waves, 6 blocks/CU. Pg triangular-packed: block m=s>>7 holds
// [16 h][128 rows][Km=(m+1)*128 t] at element offset 131072*m*(m+1).
__global__ __launch_bounds__(256, 6) void attn_qk(
    const bf16* __restrict__ qabs, const bf16* __restrict__ keys,
    const int* __restrict__ tki, const float* __restrict__ tkv,
    const float* __restrict__ logZ, bf16* __restrict__ Pg,
    float* __restrict__ kl) {
  const int s = 2047 - blockIdx.x;  // heavy-first
  const int tid = threadIdx.x;
  const int wave = tid >> 6, lane = tid & 63, g = lane >> 4, li = lane & 15;
  __shared__ int idxs[512];
  __shared__ __align__(16) bf16 ph[16 * 512];   // 16 KB staging
  __shared__ float red[64];
  __shared__ float mxf[16], dnf[16];

  for (int i = tid; i < 512; i += 256) idxs[i] = tki[(long)s * 512 + i];
  __syncthreads();

  // ---- QK^T: A-frags direct from global (L1/L2-cached), gathered B ----
  const bf16* qrow = qabs + (long)s * 9216 + li * 576 + g * 8;
  f32x4 accS[8];
  int kid[8];
  const bf16* kr[8];
  #pragma unroll
  for (int j = 0; j < 8; j++) {
    accS[j] = (f32x4){0.f,0.f,0.f,0.f};
    kid[j] = idxs[(wave * 8 + j) * 16 + li];
    kr[j] = keys + (long)kid[j] * 576 + g * 8;
  }
  short8v af = *(const short8v*)qrow;
  short8v kf[8];
  #pragma unroll
  for (int j = 0; j < 8; j++) kf[j] = *(const short8v*)kr[j];
  for (int ks = 0; ks < 18; ks++) {
    const int nko = (ks < 17 ? ks + 1 : 17) * 32;
    short8v afn = *(const short8v*)(qrow + nko);
    short8v nx[8];
    #pragma unroll
    for (int j = 0; j < 8; j++) nx[j] = *(const short8v*)(kr[j] + nko);
    #pragma unroll
    for (int j = 0; j < 8; j++) accS[j] = MFMA16(af, kf[j], accS[j]);
    af = afn;
    #pragma unroll
    for (int j = 0; j < 8; j++) kf[j] = nx[j];
  }

  // ---- scale + mask + softmax ----
  float e[8][4];
  float m4[4];
  #pragma unroll
  for (int r = 0; r < 4; r++) m4[r] = -3.4e38f;
  #pragma unroll
  for (int j = 0; j < 8; j++) {
    float mask = (kid[j] <= s) ? 0.f : NEG_;
    #pragma unroll
    for (int r = 0; r < 4; r++) {
      e[j][r] = accS[j][r] * SCALE_ + mask;
      m4[r] = fmaxf(m4[r], e[j][r]);
    }
  }
  #pragma unroll
  for (int d = 1; d < 16; d <<= 1)
    #pragma unroll
    for (int r = 0; r < 4; r++) m4[r] = fmaxf(m4[r], __shfl_xor(m4[r], d));
  if (li == 0)
    #pragma unroll
    for (int r = 0; r < 4; r++) red[wave * 16 + g * 4 + r] = m4[r];
  __syncthreads();
  if (tid < 16) mxf[tid] = fmaxf(fmaxf(red[tid], red[16 + tid]), fmaxf(red[32 + tid], red[48 + tid]));
  __syncthreads();
  float d4[4] = {0.f, 0.f, 0.f, 0.f};
  #pragma unroll
  for (int j = 0; j < 8; j++)
    #pragma unroll
    for (int r = 0; r < 4; r++) {
      e[j][r] = __expf(e[j][r] - mxf[g * 4 + r]);
      d4[r] += e[j][r];
    }
  #pragma unroll
  for (int d = 1; d < 16; d <<= 1)
    #pragma unroll
    for (int r = 0; r < 4; r++) d4[r] += __shfl_xor(d4[r], d);
  if (li == 0)
    #pragma unroll
    for (int r = 0; r < 4; r++) red[wave * 16 + g * 4 + r] = d4[r];
  __syncthreads();
  if (tid < 16) dnf[tid] = red[tid] + red[16 + tid] + red[32 + tid] + red[48 + tid];
  __syncthreads();

  float invd[4];
  #pragma unroll
  for (int r = 0; r < 4; r++) invd[r] = 1.f / dnf[g * 4 + r];

  // ---- tas + KL ----
  float tasj[8];
  #pragma unroll
  for (int j = 0; j < 8; j++) {
    float t = 0.f;
    #pragma unroll
    for (int r = 0; r < 4; r++) t += e[j][r] * invd[r];
    t += __shfl_xor(t, 16);
    t += __shfl_xor(t, 32);
    tasj[j] = t;
  }
  float klacc = 0.f;
  if (g == 0) {
    float lz = logZ[s];
    #pragma unroll
    for (int j = 0; j < 8; j++) {
      int slot = (wave * 8 + j) * 16 + li;
      float tgt = fminf(fmaxf(logf(tasj[j] * 0.0625f), -100.f), 0.f);
      float inp = fminf(fmaxf(tkv[(long)s * 512 + slot] - lz, -100.f), 0.f);
      klacc += expf(tgt) * (tgt - inp);
    }
  }
  #pragma unroll
  for (int d = 1; d < 16; d <<= 1) klacc += __shfl_xor(klacc, d);
  if (lane == 0) atomicAdd(kl, klacc);

  // ---- emit dense normalized P rows (chunked via LDS) ----
  const int m = s >> 7;
  const int Km = (m + 1) << 7;
  const int rr = s & 127;
  bf16* Pbase = Pg + 131072L * m * (m + 1);
  for (int base = 0; base < Km; base += 512) {
    const int cw = min(512, Km - base);
    __syncthreads();
    { uint4 z = {0,0,0,0};
      for (int i = tid; i < 1024; i += 256) ((uint4*)ph)[i] = z; }
    __syncthreads();
    #pragma unroll
    for (int j = 0; j < 8; j++) {
      int kk = kid[j] - base;
      if (0 <= kk && kk < 512) {
        #pragma unroll
        for (int r = 0; r < 4; r++)
          ph[(g * 4 + r) * 512 + kk] = __float2bfloat16(e[j][r] * invd[r]);
      }
    }
    __syncthreads();
    for (int u = tid; u < 1024; u += 256) {
      int h = u >> 6, c = (u & 63) * 8;
      if (c < cw)
        *(short8v*)(Pbase + ((long)(h * 128 + rr) * Km + base + c)) =
            *(const short8v*)&ph[h * 512 + c];
    }
  }
}

// ---------------- attn phase 2: dense PV GEMM (triangular-packed P) ----------------
// grid (4 n-tiles, 16 m, 16 h). out aoc[s][h*512+d] bf16.
__global__ __launch_bounds__(256) void attn_pv(const bf16* __restrict__ Pg,
                                               const bf16* __restrict__ keys,
                                               bf16* __restrict__ aoc) {
  const int m = 15 - blockIdx.y;  // heavy-first
  const int h = blockIdx.z;
  const int Km = (m + 1) << 7;
  const bf16* A = Pg + 131072L * m * (m + 1) + (long)h * 128 * Km;
  const int n0 = blockIdx.x * 128;
  __shared__ bf16 As[4096];
  __shared__ bf16 Bs[4096];
  const int tid = threadIdx.x;
  const int wave = tid >> 6, lane = tid & 63, g = lane >> 4, li = lane & 15;
  const int mB = (wave >> 1) * 64, nB = (wave & 1) * 64;
  f32x4 acc[4][4];
  #pragma unroll
  for (int i = 0; i < 4; i++)
    #pragma unroll
    for (int j = 0; j < 4; j++) acc[i][j] = (f32x4){0.f, 0.f, 0.f, 0.f};

  for (int k0 = 0; k0 < Km; k0 += 32) {
    #pragma unroll
    for (int r2 = 0; r2 < 2; r2++) {
      int idx = r2 * 256 + tid;
      int row = idx >> 2, ko = (idx & 3) * 8;
      gld16(A + (long)row * Km + k0 + ko, &As[idx * 8]);
    }
    {
      int k = tid >> 3, nb = (tid & 7) * 16;
      const bf16* src = keys + (long)(k0 + k) * 576 + n0 + nb;
      short8v v0 = *(const short8v*)src;
      short8v v1 = *(const short8v*)(src + 8);
      #pragma unroll
      for (int j = 0; j < 8; j++) {
        Bs[(nb + j) * 32 + k]     = ((const bf16*)&v0)[j];
        Bs[(nb + 8 + j) * 32 + k] = ((const bf16*)&v1)[j];
      }
    }
    __syncthreads();
    short8v af[4], bfr[4];
    #pragma unroll
    for (int mt = 0; mt < 4; mt++) af[mt]  = *(const short8v*)&As[(mB + mt*16 + li) * 32 + g*8];
    #pragma unroll
    for (int nt = 0; nt < 4; nt++) bfr[nt] = *(const short8v*)&Bs[(nB + nt*16 + li) * 32 + g*8];
    #pragma unroll
    for (int mt = 0; mt < 4; mt++)
      #pragma unroll
      for (int nt = 0; nt < 4; nt++)
        acc[mt][nt] = MFMA16(af[mt], bfr[nt], acc[mt][nt]);
    __syncthreads();
  }
  #pragma unroll
  for (int mt = 0; mt < 4; mt++)
    #pragma unroll
    for (int nt = 0; nt < 4; nt++)
      #pragma unroll
      for (int r = 0; r < 4; r++) {
        int row = m * 128 + mB + mt*16 + g*4 + r;
        int col = n0 + nB + nt*16 + li;
        aoc[(long)row * 8192 + h * 512 + col] = __float2bfloat16(acc[mt][nt][r]);
      }
}

__global__ void zero_kernel(float* p) {
  if (threadIdx.x == 0 && blockIdx.x == 0) p[0] = 0.f;
}
__global__ void copykl_kernel(const float* src, float* dst) { dst[0] = src[0]; }

// ---------------- launch ----------------
extern "C" void kernel_launch(void* const* d_in, const int* in_sizes, int n_in,
                              void* d_out, int out_size, void* d_ws, size_t ws_size,
                              hipStream_t stream) {
  (void)in_sizes; (void)n_in; (void)out_size; (void)ws_size;
  const float* x        = (const float*)d_in[0];
  const float* wq_down  = (const float*)d_in[2];
  const float* q_ln_w   = (const float*)d_in[3];
  const float* wq_up    = (const float*)d_in[4];
  const float* wkv_down = (const float*)d_in[5];
  const float* kv_ln_w  = (const float*)d_in[6];
  const float* wk_up    = (const float*)d_in[7];
  const float* wv_up    = (const float*)d_in[8];
  const float* wo       = (const float*)d_in[9];
  const float* idx_wq_b = (const float*)d_in[10];
  const float* idx_wk   = (const float*)d_in[11];
  const float* idx_kn_w = (const float*)d_in[12];
  const float* idx_kn_b = (const float*)d_in[13];
  const float* idx_ww   = (const float*)d_in[14];
  float* out = (float*)d_out;

  char* w = (char*)d_ws;
  size_t off = 0;
  auto alloc = [&](size_t bytes) { void* p = w + off; off += (bytes + 255) & ~255ul; return p; };
  // ---- persistent (live across attention) ----
  bf16* keys_b  = (bf16*)alloc(2048L*576*2);
  bf16* qabs_b  = (bf16*)alloc(2048L*9216*2);
  bf16* aoc_b   = (bf16*)alloc(2048L*8192*2);
  bf16* ao_b    = (bf16*)alloc(2048L*2048*2);
  bf16* wvu_b   = (bf16*)alloc(16L*128*512*2);
  bf16* wo_b    = (bf16*)alloc(2048L*2048*2);
  float* tkv    = (float*)alloc(2048L*512*4);
  float* logZ   = (float*)alloc(2048*4);
  float* klbuf  = (float*)alloc(64);
  int*   tki    = (int*)alloc(2048L*512*4);
  // ---- scratch region (dead before attn_qk); Pg aliases it ----
  size_t scratch0 = off;
  bf16* Pg = (bf16*)(w + scratch0);  // triangular-packed, reuses scratch
  float* qr     = (float*)alloc(2048L*1536*4);
  float* kvtmp  = (float*)alloc(2048L*576*4);
  float* kitmp  = (float*)alloc(2048L*128*4);
  float* logits = (float*)alloc(2048L*2048*4);
  float* wgt    = (float*)alloc(2048L*4*4);
  bf16* x_b     = (bf16*)alloc(2048L*2048*2);
  bf16* qr_b    = (bf16*)alloc(2048L*1536*2);
  bf16* q_b     = (bf16*)alloc(2048L*3072*2);
  bf16* qi_b    = (bf16*)alloc(2048L*512*2);
  bf16* ki_b    = (bf16*)alloc(2048L*128*2);
  bf16* wqd_b   = (bf16*)alloc(1536L*2048*2);
  bf16* wqu_b   = (bf16*)alloc(3072L*1536*2);
  bf16* wkv_b   = (bf16*)alloc(576L*2048*2);
  bf16* wku_b   = (bf16*)alloc(16L*128*512*2);
  bf16* iwq_b   = (bf16*)alloc(512L*1536*2);
  bf16* iwk_b   = (bf16*)alloc(128L*2048*2);
  // ensure scratch covers Pg
  size_t pg_end = scratch0 + 131072ul*16*17*2;
  if (off < pg_end) off = pg_end;

  dim3 b256(256);
  auto cvt = [&](const float* src, bf16* dst, long n) {
    f2b_kernel<<<(int)((n + 1023) / 1024), b256, 0, stream>>>(src, dst, n);
  };
  cvt(x, x_b, 2048L*2048);
  cvt(wq_down, wqd_b, 1536L*2048);
  cvt(wq_up, wqu_b, 3072L*1536);
  cvt(wkv_down, wkv_b, 576L*2048);
  cvt(wk_up, wku_b, 16L*128*512);
  cvt(wv_up, wvu_b, 16L*128*512);
  cvt(wo, wo_b, 2048L*2048);
  cvt(idx_wq_b, iwq_b, 512L*1536);
  cvt(idx_wk, iwk_b, 128L*2048);

  // qr = x @ wq_down^T (f32 out), rmsnorm -> qr_b
  gemm_bf16<1,0><<<dim3(12,16), b256, 0, stream>>>(x_b, wqd_b, qr, 2048,1536,2048, 2048,2048,1536, 0,0,0);
  rmsnorm_b_kernel<<<2048, b256, 0, stream>>>(qr, q_ln_w, qr_b, 1536);
  // q = qr @ wq_up^T (bf16 out)
  gemm_bf16<1,1><<<dim3(24,16), b256, 0, stream>>>(qr_b, wqu_b, q_b, 2048,3072,1536, 1536,1536,3072, 0,0,0);
  // kv = x @ wkv_down^T (f32), norm+rope -> keys_b
  gemm_bf16<1,0><<<dim3(5,16), b256, 0, stream>>>(x_b, wkv_b, kvtmp, 2048,576,2048, 2048,2048,576, 0,0,0);
  kv_norm_rope_kernel<<<2048, b256, 0, stream>>>(kvtmp, kv_ln_w, keys_b);
  // qabs: pe rope + nope batched GEMM
  rope_q_kernel<<<4096, b256, 0, stream>>>(q_b, qabs_b);
  gemm_bf16<0,1><<<dim3(4,16,16), b256, 0, stream>>>(q_b, wku_b, qabs_b, 2048,512,128, 3072,512,9216, 192, 128L*512, 576);
  // indexer q
  gemm_bf16<1,1><<<dim3(4,16), b256, 0, stream>>>(qr_b, iwq_b, qi_b, 2048,512,1536, 1536,1536,512, 0,0,0);
  rope_qi_kernel<<<1024, b256, 0, stream>>>(qi_b);
  // indexer k
  gemm_bf16<1,0><<<dim3(1,16), b256, 0, stream>>>(x_b, iwk_b, kitmp, 2048,128,2048, 2048,2048,128, 0,0,0);
  ki_ln_rope_kernel<<<2048, dim3(128), 0, stream>>>(kitmp, idx_kn_w, idx_kn_b, ki_b);
  wgt_kernel<<<2048, b256, 0, stream>>>(x, idx_ww, wgt);
  // logits + topk
  idx_logits_mfma<<<dim3(16,32), b256, 0, stream>>>(qi_b, ki_b, wgt, logits);
  topk_kernel<<<2048, b256, 0, stream>>>(logits, tki, tkv, logZ);
  // attention (split)
  zero_kernel<<<1, 64, 0, stream>>>(klbuf);
  attn_qk<<<2048, b256, 0, stream>>>(qabs_b, keys_b, tki, tkv, logZ, Pg, klbuf);
  attn_pv<<<dim3(4,16,16), b256, 0, stream>>>(Pg, keys_b, aoc_b);
  // v_up (batched) and output projection
  gemm_bf16<1,1><<<dim3(1,16,16), b256, 0, stream>>>(aoc_b, wvu_b, ao_b, 2048,128,512, 8192,512,2048, 512, 128L*512, 128);
  gemm_bf16<1,0><<<dim3(16,16), b256, 0, stream>>>(ao_b, wo_b, out, 2048,2048,2048, 2048,2048,2048, 0,0,0);
  copykl_kernel<<<1, 1, 0, stream>>>(klbuf, out + 4194304L);
}

// Round 8
// 945.753 us; speedup vs baseline: 1.0631x; 1.0631x over previous
//
#include <hip/hip_runtime.h>
#include <hip/hip_bf16.h>
#include <math.h>

typedef __hip_bfloat16 bf16;
typedef __attribute__((ext_vector_type(8))) short short8v;   // 8 x bf16 frag
typedef __attribute__((ext_vector_type(4))) float f32x4;

static constexpr float EPS_   = 1e-6f;
static constexpr float NEG_   = -1000000000.0f;
static constexpr float SCALE_ = 0.13523378f;        // (0.1*ln40+1)^2 / sqrt(192)
static constexpr float IDXSC_ = 0.08838834764832f;  // 1/sqrt(128)
static constexpr double LN10K_32 = 0.28782313662425575; // ln(10000)/32

#define MFMA16(a, b, c) __builtin_amdgcn_mfma_f32_16x16x32_bf16(a, b, c, 0, 0, 0)

// async global->LDS 16B (HW DMA, no VGPR round-trip)
__device__ __forceinline__ void gld16(const void* g, void* l) {
  __builtin_amdgcn_global_load_lds(
      (const __attribute__((address_space(1))) void*)g,
      (__attribute__((address_space(3))) void*)l, 16, 0, 0);
}

// ---------------- block reduce (sum op=0, max op=1) ----------------
static __device__ float block_reduce_op(float v, int op) {
  __shared__ float red_s[16];
  int lane = threadIdx.x & 63, wid = threadIdx.x >> 6;
  #pragma unroll
  for (int off = 32; off > 0; off >>= 1) {
    float o = __shfl_down(v, off);
    v = op ? fmaxf(v, o) : (v + o);
  }
  __syncthreads();
  if (lane == 0) red_s[wid] = v;
  __syncthreads();
  if (threadIdx.x == 0) {
    int nw = ((int)blockDim.x + 63) >> 6;
    float r = red_s[0];
    for (int i = 1; i < nw; i++) r = op ? fmaxf(r, red_s[i]) : (r + red_s[i]);
    red_s[0] = r;
  }
  __syncthreads();
  return red_s[0];
}

// ---------------- f32 -> bf16 ----------------
__global__ __launch_bounds__(256) void f2b_kernel(const float* __restrict__ in,
                                                  bf16* __restrict__ out, long n) {
  long i = ((long)blockIdx.x * 256 + threadIdx.x) * 4;
  if (i + 3 < n) {
    float4 v = *(const float4*)(in + i);
    out[i] = __float2bfloat16(v.x); out[i+1] = __float2bfloat16(v.y);
    out[i+2] = __float2bfloat16(v.z); out[i+3] = __float2bfloat16(v.w);
  } else {
    for (int j = 0; j < 4 && i + j < n; j++) out[i+j] = __float2bfloat16(in[i+j]);
  }
}

// ---------------- bf16 MFMA GEMM (global_load_lds staging, linear LDS) ----------
// BT=1: C[m,n] = sum_k A[m,k]*B[n,k];  BT=0: C[m,n] = sum_k A[m,k]*B[k,n]
// tiles 128x128, BK=32, 256 threads. M%128==0, K%32==0. OB=1 -> bf16 out.
template <int BT, int OB>
__global__ __launch_bounds__(256) void gemm_bf16(
    const bf16* __restrict__ A, const bf16* __restrict__ B, void* __restrict__ Cv,
    int M, int N, int K, int lda, int ldb, int ldc, long sA, long sB, long sC) {
  A += (long)blockIdx.z * sA;
  B += (long)blockIdx.z * sB;
  __shared__ bf16 As[4096];   // [128 rows][32 k] linear
  __shared__ bf16 Bs[4096];
  const int m0 = blockIdx.y * 128, n0 = blockIdx.x * 128;
  const int tid = threadIdx.x;
  const int wave = tid >> 6, lane = tid & 63, g = lane >> 4, li = lane & 15;
  const int mB = (wave >> 1) * 64, nB = (wave & 1) * 64;
  f32x4 acc[4][4];
  #pragma unroll
  for (int i = 0; i < 4; i++)
    #pragma unroll
    for (int j = 0; j < 4; j++) acc[i][j] = (f32x4){0.f, 0.f, 0.f, 0.f};

  for (int k0 = 0; k0 < K; k0 += 32) {
    #pragma unroll
    for (int r2 = 0; r2 < 2; r2++) {
      int idx = r2 * 256 + tid;
      int row = idx >> 2, ko = (idx & 3) * 8;
      gld16(A + (long)(m0 + row) * lda + k0 + ko, &As[idx * 8]);
    }
    if (BT) {
      #pragma unroll
      for (int r2 = 0; r2 < 2; r2++) {
        int idx = r2 * 256 + tid;
        int row = idx >> 2, ko = (idx & 3) * 8;
        int rr = n0 + row; if (rr >= N) rr = N - 1;
        gld16(B + (long)rr * ldb + k0 + ko, &Bs[idx * 8]);
      }
    } else {
      int k = tid >> 3, nb = (tid & 7) * 16;
      const bf16* src = B + (long)(k0 + k) * ldb + n0 + nb;
      short8v v0 = *(const short8v*)src;
      short8v v1 = *(const short8v*)(src + 8);
      #pragma unroll
      for (int j = 0; j < 8; j++) {
        Bs[(nb + j) * 32 + k]     = ((const bf16*)&v0)[j];
        Bs[(nb + 8 + j) * 32 + k] = ((const bf16*)&v1)[j];
      }
    }
    __syncthreads();
    short8v af[4], bfr[4];
    #pragma unroll
    for (int mt = 0; mt < 4; mt++) af[mt]  = *(const short8v*)&As[(mB + mt*16 + li) * 32 + g*8];
    #pragma unroll
    for (int nt = 0; nt < 4; nt++) bfr[nt] = *(const short8v*)&Bs[(nB + nt*16 + li) * 32 + g*8];
    #pragma unroll
    for (int mt = 0; mt < 4; mt++)
      #pragma unroll
      for (int nt = 0; nt < 4; nt++)
        acc[mt][nt] = MFMA16(af[mt], bfr[nt], acc[mt][nt]);
    __syncthreads();
  }
  #pragma unroll
  for (int mt = 0; mt < 4; mt++)
    #pragma unroll
    for (int nt = 0; nt < 4; nt++)
      #pragma unroll
      for (int r = 0; r < 4; r++) {
        int row = m0 + mB + mt*16 + g*4 + r;
        int col = n0 + nB + nt*16 + li;
        if (col < N) {
          long off = (long)blockIdx.z * sC + (long)row * ldc + col;
          if (OB) ((bf16*)Cv)[off] = __float2bfloat16(acc[mt][nt][r]);
          else    ((float*)Cv)[off] = acc[mt][nt][r];
        }
      }
}

// ---------------- rmsnorm (f32 in -> bf16 out) ----------------
__global__ __launch_bounds__(256) void rmsnorm_b_kernel(const float* __restrict__ x,
                                                        const float* __restrict__ w,
                                                        bf16* __restrict__ out, int D) {
  const float* r = x + (long)blockIdx.x * D;
  bf16* o = out + (long)blockIdx.x * D;
  float ss = 0.f;
  for (int i = threadIdx.x; i < D; i += 256) { float v = r[i]; ss = fmaf(v, v, ss); }
  ss = block_reduce_op(ss, 0);
  float sc = rsqrtf(ss / (float)D + EPS_);
  for (int i = threadIdx.x; i < D; i += 256) o[i] = __float2bfloat16(r[i] * sc * w[i]);
}

// ---------------- kv row: rmsnorm 512 + rope 64 -> keys_b[s][576] ----------------
__global__ __launch_bounds__(256) void kv_norm_rope_kernel(const float* __restrict__ kv,
                                                           const float* __restrict__ w,
                                                           bf16* __restrict__ keys_b) {
  int s = blockIdx.x;
  const float* r = kv + (long)s * 576;
  float ss = 0.f;
  for (int i = threadIdx.x; i < 512; i += 256) { float v = r[i]; ss = fmaf(v, v, ss); }
  ss = block_reduce_op(ss, 0);
  float sc = rsqrtf(ss / 512.f + EPS_);
  for (int i = threadIdx.x; i < 512; i += 256)
    keys_b[(long)s * 576 + i] = __float2bfloat16(r[i] * sc * w[i]);
  if (threadIdx.x < 32) {
    int j = threadIdx.x;
    float f = (float)exp(-(double)j * LN10K_32);
    float ang = (float)s * f;
    float c = cosf(ang), sn = sinf(ang);
    float x1 = r[512 + 2*j], x2 = r[512 + 2*j + 1];
    keys_b[(long)s * 576 + 512 + 2*j]     = __float2bfloat16(x1 * c - x2 * sn);
    keys_b[(long)s * 576 + 512 + 2*j + 1] = __float2bfloat16(x1 * sn + x2 * c);
  }
}

// ---------------- main-q rope (bf16 -> qabs_b pe region) ----------------
__global__ __launch_bounds__(256) void rope_q_kernel(const bf16* __restrict__ q,
                                                     bf16* __restrict__ qabs) {
  int idx = blockIdx.x * 256 + threadIdx.x;  // (s*16+h)*32+j
  int j = idx & 31, h = (idx >> 5) & 15, s = idx >> 9;
  float f = (float)exp(-(double)j * LN10K_32);
  float ang = (float)s * f;
  float c = cosf(ang), sn = sinf(ang);
  const bf16* src = q + (long)s * 3072 + h * 192 + 128;
  float x1 = __bfloat162float(src[2*j]), x2 = __bfloat162float(src[2*j+1]);
  bf16* dst = qabs + (long)s * 9216 + h * 576 + 512;
  dst[2*j]     = __float2bfloat16(x1 * c - x2 * sn);
  dst[2*j + 1] = __float2bfloat16(x1 * sn + x2 * c);
}

// ---------------- indexer-q half rope in place (bf16) ----------------
__global__ __launch_bounds__(256) void rope_qi_kernel(bf16* __restrict__ qi) {
  int idx = blockIdx.x * 256 + threadIdx.x;  // (s*4+ih)*32+j
  int j = idx & 31, ih = (idx >> 5) & 3, s = idx >> 7;
  float f = (float)exp(-(double)j * LN10K_32);
  float ang = (float)s * f;
  float c = cosf(ang), sn = sinf(ang);
  bf16* p = qi + (long)s * 512 + ih * 128;
  float x1 = __bfloat162float(p[j]), x2 = __bfloat162float(p[32 + j]);
  p[j]      = __float2bfloat16(x1 * c - x2 * sn);
  p[32 + j] = __float2bfloat16(x1 * sn + x2 * c);
}

// ---------------- indexer-k: layernorm + half rope -> ki_b[s][128] ----------------
__global__ __launch_bounds__(128) void ki_ln_rope_kernel(const float* __restrict__ kt,
                                                         const float* __restrict__ w,
                                                         const float* __restrict__ b,
                                                         bf16* __restrict__ ki_b) {
  int s = blockIdx.x, d = threadIdx.x;
  float v = kt[(long)s * 128 + d];
  float m = block_reduce_op(v, 0) * (1.f / 128.f);
  float dv = v - m;
  float var = block_reduce_op(dv * dv, 0) * (1.f / 128.f);
  float y = dv * rsqrtf(var + EPS_) * w[d] + b[d];
  __shared__ float ys[128];
  ys[d] = y;
  __syncthreads();
  float out;
  if (d < 64) {
    int j = d & 31;
    float f = (float)exp(-(double)j * LN10K_32);
    float ang = (float)s * f;
    float c = cosf(ang), sn = sinf(ang);
    float x1 = ys[j], x2 = ys[32 + j];
    out = (d < 32) ? (x1 * c - x2 * sn) : (x1 * sn + x2 * c);
  } else out = y;
  ki_b[(long)s * 128 + d] = __float2bfloat16(out);
}

// ---------------- gate weights: x @ idx_ww.T * 0.5 (f32) ----------------
__global__ __launch_bounds__(256) void wgt_kernel(const float* __restrict__ x,
                                                  const float* __restrict__ ww,
                                                  float* __restrict__ wgt) {
  int s = blockIdx.x;
  float a0 = 0, a1 = 0, a2 = 0, a3 = 0;
  for (int i = threadIdx.x; i < 2048; i += 256) {
    float xv = x[(long)s * 2048 + i];
    a0 = fmaf(xv, ww[i], a0);
    a1 = fmaf(xv, ww[2048 + i], a1);
    a2 = fmaf(xv, ww[4096 + i], a2);
    a3 = fmaf(xv, ww[6144 + i], a3);
  }
  a0 = block_reduce_op(a0, 0);
  a1 = block_reduce_op(a1, 0);
  a2 = block_reduce_op(a2, 0);
  a3 = block_reduce_op(a3, 0);
  if (threadIdx.x == 0) {
    wgt[s*4+0] = 0.5f*a0; wgt[s*4+1] = 0.5f*a1; wgt[s*4+2] = 0.5f*a2; wgt[s*4+3] = 0.5f*a3;
  }
}

// ---------------- indexer logits via MFMA: tile 64t x 128s ----------------
__global__ __launch_bounds__(256) void idx_logits_mfma(const bf16* __restrict__ qi,
                                                       const bf16* __restrict__ ki,
                                                       const float* __restrict__ wgt,
                                                       float* __restrict__ logits) {
  const int t0 = blockIdx.y * 64, s0 = blockIdx.x * 128;
  const int tid = threadIdx.x, wave = tid >> 6, lane = tid & 63;
  const int g = lane >> 4, li = lane & 15;
  if (s0 > t0 + 63) {  // fully causal-masked tile
    #pragma unroll
    for (int j = 0; j < 8; j++)
      #pragma unroll
      for (int r = 0; r < 4; r++) {
        int t = t0 + wave*16 + g*4 + r, sidx = s0 + j*16 + li;
        logits[(long)t * 2048 + sidx] = NEG_;
      }
    return;
  }
  f32x4 acc[8];
  #pragma unroll
  for (int j = 0; j < 8; j++) acc[j] = (f32x4){0.f,0.f,0.f,0.f};
  #pragma unroll
  for (int h = 0; h < 4; h++) {
    f32x4 tmp[8];
    #pragma unroll
    for (int j = 0; j < 8; j++) tmp[j] = (f32x4){0.f,0.f,0.f,0.f};
    const bf16* arow = qi + ((long)(t0 + wave*16 + li) * 4 + h) * 128 + g*8;
    #pragma unroll
    for (int ks = 0; ks < 4; ks++) {
      short8v a = *(const short8v*)(arow + ks*32);
      #pragma unroll
      for (int j = 0; j < 8; j++) {
        const bf16* brow = ki + (long)(s0 + j*16 + li) * 128 + ks*32 + g*8;
        tmp[j] = MFMA16(a, *(const short8v*)brow, tmp[j]);
      }
    }
    #pragma unroll
    for (int r = 0; r < 4; r++) {
      float wv = wgt[(t0 + wave*16 + g*4 + r)*4 + h];
      #pragma unroll
      for (int j = 0; j < 8; j++)
        acc[j][r] += fmaxf(tmp[j][r] * IDXSC_, 0.f) * wv;
    }
  }
  #pragma unroll
  for (int j = 0; j < 8; j++)
    #pragma unroll
    for (int r = 0; r < 4; r++) {
      int t = t0 + wave*16 + g*4 + r, sidx = s0 + j*16 + li;
      logits[(long)t * 2048 + sidx] = acc[j][r] + (sidx <= t ? 0.f : NEG_);
    }
}

// ---------------- per-row top-512 (set semantics, parallel suffix scan) --------
__global__ __launch_bounds__(256) void topk_kernel(const float* __restrict__ logits,
                                                   int* __restrict__ tki,
                                                   float* __restrict__ tkv,
                                                   float* __restrict__ logZ) {
  int t = blockIdx.x;
  const int tid = threadIdx.x;
  __shared__ unsigned skeys[2048];
  __shared__ unsigned hist[256];
  __shared__ unsigned suf[256];
  __shared__ float svals[512];
  __shared__ int s_want;
  __shared__ unsigned s_prefix;
  const float* row = logits + (long)t * 2048;
  for (int i = tid; i < 2048; i += 256) {
    unsigned u = __float_as_uint(row[i]);
    skeys[i] = (u & 0x80000000u) ? ~u : (u | 0x80000000u);
  }
  if (tid == 0) { s_want = 512; s_prefix = 0u; }
  __syncthreads();
  for (int shift = 24; shift >= 0; shift -= 8) {
    hist[tid] = 0u;
    __syncthreads();
    unsigned pmask = (shift == 24) ? 0u : (0xFFFFFFFFu << (shift + 8));
    unsigned pref = s_prefix;
    int want = s_want;
    for (int i = tid; i < 2048; i += 256) {
      unsigned k = skeys[i];
      if ((k & pmask) == pref) atomicAdd(&hist[(k >> shift) & 255u], 1u);
    }
    __syncthreads();
    // parallel inclusive suffix sum: suf[t] = sum_{b>=t} hist[b]
    suf[tid] = hist[tid];
    __syncthreads();
    #pragma unroll
    for (int d = 1; d < 256; d <<= 1) {
      unsigned v = suf[tid];
      unsigned add = (tid + d < 256) ? suf[tid + d] : 0u;
      __syncthreads();
      suf[tid] = v + add;
      __syncthreads();
    }
    unsigned Sb = suf[tid];
    unsigned Sb1 = (tid < 255) ? suf[tid + 1] : 0u;
    if ((int)Sb >= want && (int)Sb1 < want) {
      s_want = want - (int)Sb1;
      s_prefix = pref | ((unsigned)tid << shift);
    }
    __syncthreads();
  }
  unsigned T = s_prefix;
  int want_eq = s_want;
  int c_gt = 512 - want_eq;
  if (tid < 64) {
    int n_gt = 0, n_eq = 0;
    unsigned long long below = (1ull << tid) - 1ull;
    for (int base = 0; base < 2048; base += 64) {
      int i = base + (int)tid;
      unsigned k = skeys[i];
      bool gt = (k > T), eq = (k == T);
      unsigned long long bg = __ballot(gt);
      unsigned long long be = __ballot(eq);
      int slot = -1;
      if (gt) slot = n_gt + (int)__popcll(bg & below);
      else if (eq) {
        int er = n_eq + (int)__popcll(be & below);
        if (er < want_eq) slot = c_gt + er;
      }
      if (slot >= 0) {
        unsigned bits = (k & 0x80000000u) ? (k ^ 0x80000000u) : ~k;
        float val = __uint_as_float(bits);
        tki[(long)t * 512 + slot] = i;
        tkv[(long)t * 512 + slot] = val;
        svals[slot] = val;
      }
      n_gt += (int)__popcll(bg);
      n_eq += (int)__popcll(be);
    }
  }
  __syncthreads();
  float m = -3.4e38f;
  for (int i = tid; i < 512; i += 256) m = fmaxf(m, svals[i]);
  m = block_reduce_op(m, 1);
  float se = 0.f;
  for (int i = tid; i < 512; i += 256) se += expf(svals[i] - m);
  se = block_reduce_op(se, 0);
  if (tid == 0) logZ[t] = m + logf(se);
}

// ---------------- attn phase 1: QK^T + softmax + KL + dense-P emit ----------------
// 1 query/block, 4 waves. Distance-2 prefetch on gathered K frags.
__global__ __launch_bounds__(256, 4) void attn_qk(
    const bf16* __restrict__ qabs, const bf16* __restrict__ keys,
    const int* __restrict__ tki, const float* __restrict__ tkv,
    const float* __restrict__ logZ, bf16* __restrict__ Pg,
    float* __restrict__ kl) {
  const int s = 2047 - blockIdx.x;  // heavy-first
  const int tid = threadIdx.x;
  const int wave = tid >> 6, lane = tid & 63, g = lane >> 4, li = lane & 15;
  __shared__ int idxs[512];
  __shared__ __align__(16) bf16 ph[16 * 512];   // 16 KB staging
  __shared__ float red[64];
  __shared__ float mxf[16], dnf[16];

  for (int i = tid; i < 512; i += 256) idxs[i] = tki[(long)s * 512 + i];
  __syncthreads();

  // ---- QK^T: A-frags direct from global, gathered B, prefetch depth 2 ----
  const bf16* qrow = qabs + (long)s * 9216 + li * 576 + g * 8;
  f32x4 accS[8];
  int kid[8];
  const bf16* kr[8];
  #pragma unroll
  for (int j = 0; j < 8; j++) {
    accS[j] = (f32x4){0.f,0.f,0.f,0.f};
    kid[j] = idxs[(wave * 8 + j) * 16 + li];
    kr[j] = keys + (long)kid[j] * 576 + g * 8;
  }
  short8v afv[2];
  short8v kfv[2][8];
  afv[0] = *(const short8v*)qrow;
  afv[1] = *(const short8v*)(qrow + 32);
  #pragma unroll
  for (int j = 0; j < 8; j++) kfv[0][j] = *(const short8v*)kr[j];
  #pragma unroll
  for (int j = 0; j < 8; j++) kfv[1][j] = *(const short8v*)(kr[j] + 32);
  #pragma unroll
  for (int ks = 0; ks < 18; ks++) {
    const int cur = ks & 1;
    const int nko = (ks + 2 < 18 ? ks + 2 : 17) * 32;
    short8v anx = *(const short8v*)(qrow + nko);
    short8v nx[8];
    #pragma unroll
    for (int j = 0; j < 8; j++) nx[j] = *(const short8v*)(kr[j] + nko);
    #pragma unroll
    for (int j = 0; j < 8; j++) accS[j] = MFMA16(afv[cur], kfv[cur][j], accS[j]);
    afv[cur] = anx;
    #pragma unroll
    for (int j = 0; j < 8; j++) kfv[cur][j] = nx[j];
  }

  // ---- scale + mask + softmax ----
  float e[8][4];
  float m4[4];
  #pragma unroll
  for (int r = 0; r < 4; r++) m4[r] = -3.4e38f;
  #pragma unroll
  for (int j = 0; j < 8; j++) {
    float mask = (kid[j] <= s) ? 0.f : NEG_;
    #pragma unroll
    for (int r = 0; r < 4; r++) {
      e[j][r] = accS[j][r] * SCALE_ + mask;
      m4[r] = fmaxf(m4[r], e[j][r]);
    }
  }
  #pragma unroll
  for (int d = 1; d < 16; d <<= 1)
    #pragma unroll
    for (int r = 0; r < 4; r++) m4[r] = fmaxf(m4[r], __shfl_xor(m4[r], d));
  if (li == 0)
    #pragma unroll
    for (int r = 0; r < 4; r++) red[wave * 16 + g * 4 + r] = m4[r];
  __syncthreads();
  if (tid < 16) mxf[tid] = fmaxf(fmaxf(red[tid], red[16 + tid]), fmaxf(red[32 + tid], red[48 + tid]));
  __syncthreads();
  float d4[4] = {0.f, 0.f, 0.f, 0.f};
  #pragma unroll
  for (int j = 0; j < 8; j++)
    #pragma unroll
    for (int r = 0; r < 4; r++) {
      e[j][r] = __expf(e[j][r] - mxf[g * 4 + r]);
      d4[r] += e[j][r];
    }
  #pragma unroll
  for (int d = 1; d < 16; d <<= 1)
    #pragma unroll
    for (int r = 0; r < 4; r++) d4[r] += __shfl_xor(d4[r], d);
  if (li == 0)
    #pragma unroll
    for (int r = 0; r < 4; r++) red[wave * 16 + g * 4 + r] = d4[r];
  __syncthreads();
  if (tid < 16) dnf[tid] = red[tid] + red[16 + tid] + red[32 + tid] + red[48 + tid];
  __syncthreads();

  float invd[4];
  #pragma unroll
  for (int r = 0; r < 4; r++) invd[r] = 1.f / dnf[g * 4 + r];

  // ---- tas + KL ----
  float tasj[8];
  #pragma unroll
  for (int j = 0; j < 8; j++) {
    float t = 0.f;
    #pragma unroll
    for (int r = 0; r < 4; r++) t += e[j][r] * invd[r];
    t += __shfl_xor(t, 16);
    t += __shfl_xor(t, 32);
    tasj[j] = t;
  }
  float klacc = 0.f;
  if (g == 0) {
    float lz = logZ[s];
    #pragma unroll
    for (int j = 0; j < 8; j++) {
      int slot = (wave * 8 + j) * 16 + li;
      float tgt = fminf(fmaxf(logf(tasj[j] * 0.0625f), -100.f), 0.f);
      float inp = fminf(fmaxf(tkv[(long)s * 512 + slot] - lz, -100.f), 0.f);
      klacc += expf(tgt) * (tgt - inp);
    }
  }
  #pragma unroll
  for (int d = 1; d < 16; d <<= 1) klacc += __shfl_xor(klacc, d);
  if (lane == 0) atomicAdd(kl, klacc);

  // ---- emit dense normalized P rows (chunked via LDS) ----
  const int m = s >> 7;
  const int Km = (m + 1) << 7;
  const int rr = s & 127;
  bf16* Pbase = Pg + 131072L * m * (m + 1);
  for (int base = 0; base < Km; base += 512) {
    const int cw = min(512, Km - base);
    __syncthreads();
    { uint4 z = {0,0,0,0};
      for (int i = tid; i < 1024; i += 256) ((uint4*)ph)[i] = z; }
    __syncthreads();
    #pragma unroll
    for (int j = 0; j < 8; j++) {
      int kk = kid[j] - base;
      if (0 <= kk && kk < 512) {
        #pragma unroll
        for (int r = 0; r < 4; r++)
          ph[(g * 4 + r) * 512 + kk] = __float2bfloat16(e[j][r] * invd[r]);
      }
    }
    __syncthreads();
    for (int u = tid; u < 1024; u += 256) {
      int h = u >> 6, c = (u & 63) * 8;
      if (c < cw)
        *(short8v*)(Pbase + ((long)(h * 128 + rr) * Km + base + c)) =
            *(const short8v*)&ph[h * 512 + c];
    }
  }
}

// ---------------- attn phase 2: dense PV GEMM (triangular-packed P) ----------------
// grid (4 n-tiles, 16 m, 16 h). out aoc[s][h*512+d] bf16.
__global__ __launch_bounds__(256) void attn_pv(const bf16* __restrict__ Pg,
                                               const bf16* __restrict__ keys,
                                               bf16* __restrict__ aoc) {
  const int m = 15 - blockIdx.y;  // heavy-first
  const int h = blockIdx.z;
  const int Km = (m + 1) << 7;
  const bf16* A = Pg + 131072L * m * (m + 1) + (long)h * 128 * Km;
  const int n0 = blockIdx.x * 128;
  __shared__ bf16 As[4096];
  __shared__ bf16 Bs[4096];
  const int tid = threadIdx.x;
  const int wave = tid >> 6, lane = tid & 63, g = lane >> 4, li = lane & 15;
  const int mB = (wave >> 1) * 64, nB = (wave & 1) * 64;
  f32x4 acc[4][4];
  #pragma unroll
  for (int i = 0; i < 4; i++)
    #pragma unroll
    for (int j = 0; j < 4; j++) acc[i][j] = (f32x4){0.f, 0.f, 0.f, 0.f};

  for (int k0 = 0; k0 < Km; k0 += 32) {
    #pragma unroll
    for (int r2 = 0; r2 < 2; r2++) {
      int idx = r2 * 256 + tid;
      int row = idx >> 2, ko = (idx & 3) * 8;
      gld16(A + (long)row * Km + k0 + ko, &As[idx * 8]);
    }
    {
      int k = tid >> 3, nb = (tid & 7) * 16;
      const bf16* src = keys + (long)(k0 + k) * 576 + n0 + nb;
      short8v v0 = *(const short8v*)src;
      short8v v1 = *(const short8v*)(src + 8);
      #pragma unroll
      for (int j = 0; j < 8; j++) {
        Bs[(nb + j) * 32 + k]     = ((const bf16*)&v0)[j];
        Bs[(nb + 8 + j) * 32 + k] = ((const bf16*)&v1)[j];
      }
    }
    __syncthreads();
    short8v af[4], bfr[4];
    #pragma unroll
    for (int mt = 0; mt < 4; mt++) af[mt]  = *(const short8v*)&As[(mB + mt*16 + li) * 32 + g*8];
    #pragma unroll
    for (int nt = 0; nt < 4; nt++) bfr[nt] = *(const short8v*)&Bs[(nB + nt*16 + li) * 32 + g*8];
    #pragma unroll
    for (int mt = 0; mt < 4; mt++)
      #pragma unroll
      for (int nt = 0; nt < 4; nt++)
        acc[mt][nt] = MFMA16(af[mt], bfr[nt], acc[mt][nt]);
    __syncthreads();
  }
  #pragma unroll
  for (int mt = 0; mt < 4; mt++)
    #pragma unroll
    for (int nt = 0; nt < 4; nt++)
      #pragma unroll
      for (int r = 0; r < 4; r++) {
        int row = m * 128 + mB + mt*16 + g*4 + r;
        int col = n0 + nB + nt*16 + li;
        aoc[(long)row * 8192 + h * 512 + col] = __float2bfloat16(acc[mt][nt][r]);
      }
}

__global__ void zero_kernel(float* p) {
  if (threadIdx.x == 0 && blockIdx.x == 0) p[0] = 0.f;
}
__global__ void copykl_kernel(const float* src, float* dst) { dst[0] = src[0]; }

// ---------------- launch ----------------
extern "C" void kernel_launch(void* const* d_in, const int* in_sizes, int n_in,
                              void* d_out, int out_size, void* d_ws, size_t ws_size,
                              hipStream_t stream) {
  (void)in_sizes; (void)n_in; (void)out_size; (void)ws_size;
  const float* x        = (const float*)d_in[0];
  const float* wq_down  = (const float*)d_in[2];
  const float* q_ln_w   = (const float*)d_in[3];
  const float* wq_up    = (const float*)d_in[4];
  const float* wkv_down = (const float*)d_in[5];
  const float* kv_ln_w  = (const float*)d_in[6];
  const float* wk_up    = (const float*)d_in[7];
  const float* wv_up    = (const float*)d_in[8];
  const float* wo       = (const float*)d_in[9];
  const float* idx_wq_b = (const float*)d_in[10];
  const float* idx_wk   = (const float*)d_in[11];
  const float* idx_kn_w = (const float*)d_in[12];
  const float* idx_kn_b = (const float*)d_in[13];
  const float* idx_ww   = (const float*)d_in[14];
  float* out = (float*)d_out;

  char* w = (char*)d_ws;
  size_t off = 0;
  auto alloc = [&](size_t bytes) { void* p = w + off; off += (bytes + 255) & ~255ul; return p; };
  // ---- persistent (live across attention) ----
  bf16* keys_b  = (bf16*)alloc(2048L*576*2);
  bf16* qabs_b  = (bf16*)alloc(2048L*9216*2);
  bf16* aoc_b   = (bf16*)alloc(2048L*8192*2);
  bf16* ao_b    = (bf16*)alloc(2048L*2048*2);
  bf16* wvu_b   = (bf16*)alloc(16L*128*512*2);
  bf16* wo_b    = (bf16*)alloc(2048L*2048*2);
  float* tkv    = (float*)alloc(2048L*512*4);
  float* logZ   = (float*)alloc(2048*4);
  float* klbuf  = (float*)alloc(64);
  int*   tki    = (int*)alloc(2048L*512*4);
  // ---- scratch region (dead before attn_qk); Pg aliases it ----
  size_t scratch0 = off;
  bf16* Pg = (bf16*)(w + scratch0);  // triangular-packed, reuses scratch
  float* qr     = (float*)alloc(2048L*1536*4);
  float* kvtmp  = (float*)alloc(2048L*576*4);
  float* kitmp  = (float*)alloc(2048L*128*4);
  float* logits = (float*)alloc(2048L*2048*4);
  float* wgt    = (float*)alloc(2048L*4*4);
  bf16* x_b     = (bf16*)alloc(2048L*2048*2);
  bf16* qr_b    = (bf16*)alloc(2048L*1536*2);
  bf16* q_b     = (bf16*)alloc(2048L*3072*2);
  bf16* qi_b    = (bf16*)alloc(2048L*512*2);
  bf16* ki_b    = (bf16*)alloc(2048L*128*2);
  bf16* wqd_b   = (bf16*)alloc(1536L*2048*2);
  bf16* wqu_b   = (bf16*)alloc(3072L*1536*2);
  bf16* wkv_b   = (bf16*)alloc(576L*2048*2);
  bf16* wku_b   = (bf16*)alloc(16L*128*512*2);
  bf16* iwq_b   = (bf16*)alloc(512L*1536*2);
  bf16* iwk_b   = (bf16*)alloc(128L*2048*2);
  // ensure scratch covers Pg
  size_t pg_end = scratch0 + 131072ul*16*17*2;
  if (off < pg_end) off = pg_end;

  dim3 b256(256);
  auto cvt = [&](const float* src, bf16* dst, long n) {
    f2b_kernel<<<(int)((n + 1023) / 1024), b256, 0, stream>>>(src, dst, n);
  };
  cvt(x, x_b, 2048L*2048);
  cvt(wq_down, wqd_b, 1536L*2048);
  cvt(wq_up, wqu_b, 3072L*1536);
  cvt(wkv_down, wkv_b, 576L*2048);
  cvt(wk_up, wku_b, 16L*128*512);
  cvt(wv_up, wvu_b, 16L*128*512);
  cvt(wo, wo_b, 2048L*2048);
  cvt(idx_wq_b, iwq_b, 512L*1536);
  cvt(idx_wk, iwk_b, 128L*2048);

  // qr = x @ wq_down^T (f32 out), rmsnorm -> qr_b
  gemm_bf16<1,0><<<dim3(12,16), b256, 0, stream>>>(x_b, wqd_b, qr, 2048,1536,2048, 2048,2048,1536, 0,0,0);
  rmsnorm_b_kernel<<<2048, b256, 0, stream>>>(qr, q_ln_w, qr_b, 1536);
  // q = qr @ wq_up^T (bf16 out)
  gemm_bf16<1,1><<<dim3(24,16), b256, 0, stream>>>(qr_b, wqu_b, q_b, 2048,3072,1536, 1536,1536,3072, 0,0,0);
  // kv = x @ wkv_down^T (f32), norm+rope -> keys_b
  gemm_bf16<1,0><<<dim3(5,16), b256, 0, stream>>>(x_b, wkv_b, kvtmp, 2048,576,2048, 2048,2048,576, 0,0,0);
  kv_norm_rope_kernel<<<2048, b256, 0, stream>>>(kvtmp, kv_ln_w, keys_b);
  // qabs: pe rope + nope batched GEMM
  rope_q_kernel<<<4096, b256, 0, stream>>>(q_b, qabs_b);
  gemm_bf16<0,1><<<dim3(4,16,16), b256, 0, stream>>>(q_b, wku_b, qabs_b, 2048,512,128, 3072,512,9216, 192, 128L*512, 576);
  // indexer q
  gemm_bf16<1,1><<<dim3(4,16), b256, 0, stream>>>(qr_b, iwq_b, qi_b, 2048,512,1536, 1536,1536,512, 0,0,0);
  rope_qi_kernel<<<1024, b256, 0, stream>>>(qi_b);
  // indexer k
  gemm_bf16<1,0><<<dim3(1,16), b256, 0, stream>>>(x_b, iwk_b, kitmp, 2048,128,2048, 2048,2048,128, 0,0,0);
  ki_ln_rope_kernel<<<2048, dim3(128), 0, stream>>>(kitmp, idx_kn_w, idx_kn_b, ki_b);
  wgt_kernel<<<2048, b256, 0, stream>>>(x, idx_ww, wgt);
  // logits + topk
  idx_logits_mfma<<<dim3(16,32), b256, 0, stream>>>(qi_b, ki_b, wgt, logits);
  topk_kernel<<<2048, b256, 0, stream>>>(logits, tki, tkv, logZ);
  // attention (split)
  zero_kernel<<<1, 64, 0, stream>>>(klbuf);
  attn_qk<<<2048, b256, 0, stream>>>(qabs_b, keys_b, tki, tkv, logZ, Pg, klbuf);
  attn_pv<<<dim3(4,16,16), b256, 0, stream>>>(Pg, keys_b, aoc_b);
  // v_up (batched) and output projection
  gemm_bf16<1,1><<<dim3(1,16,16), b256, 0, stream>>>(aoc_b, wvu_b, ao_b, 2048,128,512, 8192,512,2048, 512, 128L*512, 128);
  gemm_bf16<1,0><<<dim3(16,16), b256, 0, stream>>>(ao_b, wo_b, out, 2048,2048,2048, 2048,2048,2048, 0,0,0);
  copykl_kernel<<<1, 1, 0, stream>>>(klbuf, out + 4194304L);
}

// Round 9
// 914.213 us; speedup vs baseline: 1.0998x; 1.0345x over previous
//
#include <hip/hip_runtime.h>
#include <hip/hip_bf16.h>
#include <math.h>

typedef __hip_bfloat16 bf16;
typedef __attribute__((ext_vector_type(8))) short short8v;   // 8 x bf16 frag
typedef __attribute__((ext_vector_type(4))) float f32x4;

static constexpr float EPS_   = 1e-6f;
static constexpr float NEG_   = -1000000000.0f;
static constexpr float SCALE_ = 0.13523378f;        // (0.1*ln40+1)^2 / sqrt(192)
static constexpr float IDXSC_ = 0.08838834764832f;  // 1/sqrt(128)
static constexpr double LN10K_32 = 0.28782313662425575; // ln(10000)/32

#define MFMA16(a, b, c) __builtin_amdgcn_mfma_f32_16x16x32_bf16(a, b, c, 0, 0, 0)

// async global->LDS 16B (HW DMA, no VGPR round-trip)
__device__ __forceinline__ void gld16(const void* g, void* l) {
  __builtin_amdgcn_global_load_lds(
      (const __attribute__((address_space(1))) void*)g,
      (__attribute__((address_space(3))) void*)l, 16, 0, 0);
}

// ---------------- block reduce (sum op=0, max op=1) ----------------
static __device__ float block_reduce_op(float v, int op) {
  __shared__ float red_s[16];
  int lane = threadIdx.x & 63, wid = threadIdx.x >> 6;
  #pragma unroll
  for (int off = 32; off > 0; off >>= 1) {
    float o = __shfl_down(v, off);
    v = op ? fmaxf(v, o) : (v + o);
  }
  __syncthreads();
  if (lane == 0) red_s[wid] = v;
  __syncthreads();
  if (threadIdx.x == 0) {
    int nw = ((int)blockDim.x + 63) >> 6;
    float r = red_s[0];
    for (int i = 1; i < nw; i++) r = op ? fmaxf(r, red_s[i]) : (r + red_s[i]);
    red_s[0] = r;
  }
  __syncthreads();
  return red_s[0];
}

// ---------------- merged f32 -> bf16 (9 segments, one launch) ----------------
struct CvtSeg { const float* s; bf16* d; long n; };
struct CvtArgs { CvtSeg seg[9]; };
__global__ __launch_bounds__(256) void f2b_multi(CvtArgs a) {
  for (int k = 0; k < 9; k++) {
    const float* __restrict__ src = a.seg[k].s;
    bf16* __restrict__ dst = a.seg[k].d;
    long n4 = a.seg[k].n >> 2;
    for (long i = (long)blockIdx.x * 256 + threadIdx.x; i < n4; i += (long)gridDim.x * 256) {
      float4 v = *(const float4*)(src + i * 4);
      dst[i*4]   = __float2bfloat16(v.x);
      dst[i*4+1] = __float2bfloat16(v.y);
      dst[i*4+2] = __float2bfloat16(v.z);
      dst[i*4+3] = __float2bfloat16(v.w);
    }
  }
}

// ---------------- bf16 MFMA GEMM (global_load_lds staging, linear LDS) ----------
// BT=1: C[m,n] = sum_k A[m,k]*B[n,k];  BT=0: C[m,n] = sum_k A[m,k]*B[k,n]
// tiles 128x128, BK=32, 256 threads. M%128==0, K%32==0. OB=1 -> bf16 out.
template <int BT, int OB>
__global__ __launch_bounds__(256) void gemm_bf16(
    const bf16* __restrict__ A, const bf16* __restrict__ B, void* __restrict__ Cv,
    int M, int N, int K, int lda, int ldb, int ldc, long sA, long sB, long sC) {
  A += (long)blockIdx.z * sA;
  B += (long)blockIdx.z * sB;
  __shared__ bf16 As[4096];   // [128 rows][32 k] linear
  __shared__ bf16 Bs[4096];
  const int m0 = blockIdx.y * 128, n0 = blockIdx.x * 128;
  const int tid = threadIdx.x;
  const int wave = tid >> 6, lane = tid & 63, g = lane >> 4, li = lane & 15;
  const int mB = (wave >> 1) * 64, nB = (wave & 1) * 64;
  f32x4 acc[4][4];
  #pragma unroll
  for (int i = 0; i < 4; i++)
    #pragma unroll
    for (int j = 0; j < 4; j++) acc[i][j] = (f32x4){0.f, 0.f, 0.f, 0.f};

  for (int k0 = 0; k0 < K; k0 += 32) {
    #pragma unroll
    for (int r2 = 0; r2 < 2; r2++) {
      int idx = r2 * 256 + tid;
      int row = idx >> 2, ko = (idx & 3) * 8;
      gld16(A + (long)(m0 + row) * lda + k0 + ko, &As[idx * 8]);
    }
    if (BT) {
      #pragma unroll
      for (int r2 = 0; r2 < 2; r2++) {
        int idx = r2 * 256 + tid;
        int row = idx >> 2, ko = (idx & 3) * 8;
        int rr = n0 + row; if (rr >= N) rr = N - 1;
        gld16(B + (long)rr * ldb + k0 + ko, &Bs[idx * 8]);
      }
    } else {
      int k = tid >> 3, nb = (tid & 7) * 16;
      const bf16* src = B + (long)(k0 + k) * ldb + n0 + nb;
      short8v v0 = *(const short8v*)src;
      short8v v1 = *(const short8v*)(src + 8);
      #pragma unroll
      for (int j = 0; j < 8; j++) {
        Bs[(nb + j) * 32 + k]     = ((const bf16*)&v0)[j];
        Bs[(nb + 8 + j) * 32 + k] = ((const bf16*)&v1)[j];
      }
    }
    __syncthreads();
    short8v af[4], bfr[4];
    #pragma unroll
    for (int mt = 0; mt < 4; mt++) af[mt]  = *(const short8v*)&As[(mB + mt*16 + li) * 32 + g*8];
    #pragma unroll
    for (int nt = 0; nt < 4; nt++) bfr[nt] = *(const short8v*)&Bs[(nB + nt*16 + li) * 32 + g*8];
    #pragma unroll
    for (int mt = 0; mt < 4; mt++)
      #pragma unroll
      for (int nt = 0; nt < 4; nt++)
        acc[mt][nt] = MFMA16(af[mt], bfr[nt], acc[mt][nt]);
    __syncthreads();
  }
  #pragma unroll
  for (int mt = 0; mt < 4; mt++)
    #pragma unroll
    for (int nt = 0; nt < 4; nt++)
      #pragma unroll
      for (int r = 0; r < 4; r++) {
        int row = m0 + mB + mt*16 + g*4 + r;
        int col = n0 + nB + nt*16 + li;
        if (col < N) {
          long off = (long)blockIdx.z * sC + (long)row * ldc + col;
          if (OB) ((bf16*)Cv)[off] = __float2bfloat16(acc[mt][nt][r]);
          else    ((float*)Cv)[off] = acc[mt][nt][r];
        }
      }
}

// ---------------- rmsnorm (f32 in -> bf16 out) ----------------
__global__ __launch_bounds__(256) void rmsnorm_b_kernel(const float* __restrict__ x,
                                                        const float* __restrict__ w,
                                                        bf16* __restrict__ out, int D) {
  const float* r = x + (long)blockIdx.x * D;
  bf16* o = out + (long)blockIdx.x * D;
  float ss = 0.f;
  for (int i = threadIdx.x; i < D; i += 256) { float v = r[i]; ss = fmaf(v, v, ss); }
  ss = block_reduce_op(ss, 0);
  float sc = rsqrtf(ss / (float)D + EPS_);
  for (int i = threadIdx.x; i < D; i += 256) o[i] = __float2bfloat16(r[i] * sc * w[i]);
}

// ---------------- kv row: rmsnorm 512 + rope 64 -> keys_b[s][576] ----------------
__global__ __launch_bounds__(256) void kv_norm_rope_kernel(const float* __restrict__ kv,
                                                           const float* __restrict__ w,
                                                           bf16* __restrict__ keys_b) {
  int s = blockIdx.x;
  const float* r = kv + (long)s * 576;
  float ss = 0.f;
  for (int i = threadIdx.x; i < 512; i += 256) { float v = r[i]; ss = fmaf(v, v, ss); }
  ss = block_reduce_op(ss, 0);
  float sc = rsqrtf(ss / 512.f + EPS_);
  for (int i = threadIdx.x; i < 512; i += 256)
    keys_b[(long)s * 576 + i] = __float2bfloat16(r[i] * sc * w[i]);
  if (threadIdx.x < 32) {
    int j = threadIdx.x;
    float f = (float)exp(-(double)j * LN10K_32);
    float ang = (float)s * f;
    float c = cosf(ang), sn = sinf(ang);
    float x1 = r[512 + 2*j], x2 = r[512 + 2*j + 1];
    keys_b[(long)s * 576 + 512 + 2*j]     = __float2bfloat16(x1 * c - x2 * sn);
    keys_b[(long)s * 576 + 512 + 2*j + 1] = __float2bfloat16(x1 * sn + x2 * c);
  }
}

// ---------------- main-q rope (bf16 -> qabs_b pe region) ----------------
__global__ __launch_bounds__(256) void rope_q_kernel(const bf16* __restrict__ q,
                                                     bf16* __restrict__ qabs) {
  int idx = blockIdx.x * 256 + threadIdx.x;  // (s*16+h)*32+j
  int j = idx & 31, h = (idx >> 5) & 15, s = idx >> 9;
  float f = (float)exp(-(double)j * LN10K_32);
  float ang = (float)s * f;
  float c = cosf(ang), sn = sinf(ang);
  const bf16* src = q + (long)s * 3072 + h * 192 + 128;
  float x1 = __bfloat162float(src[2*j]), x2 = __bfloat162float(src[2*j+1]);
  bf16* dst = qabs + (long)s * 9216 + h * 576 + 512;
  dst[2*j]     = __float2bfloat16(x1 * c - x2 * sn);
  dst[2*j + 1] = __float2bfloat16(x1 * sn + x2 * c);
}

// ---------------- indexer-q half rope in place (bf16) ----------------
__global__ __launch_bounds__(256) void rope_qi_kernel(bf16* __restrict__ qi) {
  int idx = blockIdx.x * 256 + threadIdx.x;  // (s*4+ih)*32+j
  int j = idx & 31, ih = (idx >> 5) & 3, s = idx >> 7;
  float f = (float)exp(-(double)j * LN10K_32);
  float ang = (float)s * f;
  float c = cosf(ang), sn = sinf(ang);
  bf16* p = qi + (long)s * 512 + ih * 128;
  float x1 = __bfloat162float(p[j]), x2 = __bfloat162float(p[32 + j]);
  p[j]      = __float2bfloat16(x1 * c - x2 * sn);
  p[32 + j] = __float2bfloat16(x1 * sn + x2 * c);
}

// ---------------- indexer-k: layernorm + half rope -> ki_b[s][128] ----------------
__global__ __launch_bounds__(128) void ki_ln_rope_kernel(const float* __restrict__ kt,
                                                         const float* __restrict__ w,
                                                         const float* __restrict__ b,
                                                         bf16* __restrict__ ki_b) {
  int s = blockIdx.x, d = threadIdx.x;
  float v = kt[(long)s * 128 + d];
  float m = block_reduce_op(v, 0) * (1.f / 128.f);
  float dv = v - m;
  float var = block_reduce_op(dv * dv, 0) * (1.f / 128.f);
  float y = dv * rsqrtf(var + EPS_) * w[d] + b[d];
  __shared__ float ys[128];
  ys[d] = y;
  __syncthreads();
  float out;
  if (d < 64) {
    int j = d & 31;
    float f = (float)exp(-(double)j * LN10K_32);
    float ang = (float)s * f;
    float c = cosf(ang), sn = sinf(ang);
    float x1 = ys[j], x2 = ys[32 + j];
    out = (d < 32) ? (x1 * c - x2 * sn) : (x1 * sn + x2 * c);
  } else out = y;
  ki_b[(long)s * 128 + d] = __float2bfloat16(out);
}

// ---------------- gate weights: x @ idx_ww.T * 0.5 (f32) ----------------
__global__ __launch_bounds__(256) void wgt_kernel(const float* __restrict__ x,
                                                  const float* __restrict__ ww,
                                                  float* __restrict__ wgt) {
  int s = blockIdx.x;
  float a0 = 0, a1 = 0, a2 = 0, a3 = 0;
  for (int i = threadIdx.x; i < 2048; i += 256) {
    float xv = x[(long)s * 2048 + i];
    a0 = fmaf(xv, ww[i], a0);
    a1 = fmaf(xv, ww[2048 + i], a1);
    a2 = fmaf(xv, ww[4096 + i], a2);
    a3 = fmaf(xv, ww[6144 + i], a3);
  }
  a0 = block_reduce_op(a0, 0);
  a1 = block_reduce_op(a1, 0);
  a2 = block_reduce_op(a2, 0);
  a3 = block_reduce_op(a3, 0);
  if (threadIdx.x == 0) {
    wgt[s*4+0] = 0.5f*a0; wgt[s*4+1] = 0.5f*a1; wgt[s*4+2] = 0.5f*a2; wgt[s*4+3] = 0.5f*a3;
  }
}

// ---------------- indexer logits via MFMA: tile 64t x 128s ----------------
__global__ __launch_bounds__(256) void idx_logits_mfma(const bf16* __restrict__ qi,
                                                       const bf16* __restrict__ ki,
                                                       const float* __restrict__ wgt,
                                                       float* __restrict__ logits) {
  const int t0 = blockIdx.y * 64, s0 = blockIdx.x * 128;
  const int tid = threadIdx.x, wave = tid >> 6, lane = tid & 63;
  const int g = lane >> 4, li = lane & 15;
  if (s0 > t0 + 63) {  // fully causal-masked tile
    #pragma unroll
    for (int j = 0; j < 8; j++)
      #pragma unroll
      for (int r = 0; r < 4; r++) {
        int t = t0 + wave*16 + g*4 + r, sidx = s0 + j*16 + li;
        logits[(long)t * 2048 + sidx] = NEG_;
      }
    return;
  }
  f32x4 acc[8];
  #pragma unroll
  for (int j = 0; j < 8; j++) acc[j] = (f32x4){0.f,0.f,0.f,0.f};
  #pragma unroll
  for (int h = 0; h < 4; h++) {
    f32x4 tmp[8];
    #pragma unroll
    for (int j = 0; j < 8; j++) tmp[j] = (f32x4){0.f,0.f,0.f,0.f};
    const bf16* arow = qi + ((long)(t0 + wave*16 + li) * 4 + h) * 128 + g*8;
    #pragma unroll
    for (int ks = 0; ks < 4; ks++) {
      short8v a = *(const short8v*)(arow + ks*32);
      #pragma unroll
      for (int j = 0; j < 8; j++) {
        const bf16* brow = ki + (long)(s0 + j*16 + li) * 128 + ks*32 + g*8;
        tmp[j] = MFMA16(a, *(const short8v*)brow, tmp[j]);
      }
    }
    #pragma unroll
    for (int r = 0; r < 4; r++) {
      float wv = wgt[(t0 + wave*16 + g*4 + r)*4 + h];
      #pragma unroll
      for (int j = 0; j < 8; j++)
        acc[j][r] += fmaxf(tmp[j][r] * IDXSC_, 0.f) * wv;
    }
  }
  #pragma unroll
  for (int j = 0; j < 8; j++)
    #pragma unroll
    for (int r = 0; r < 4; r++) {
      int t = t0 + wave*16 + g*4 + r, sidx = s0 + j*16 + li;
      logits[(long)t * 2048 + sidx] = acc[j][r] + (sidx <= t ? 0.f : NEG_);
    }
}

// ---------------- per-row top-512 (set semantics, parallel suffix scan) --------
__global__ __launch_bounds__(256) void topk_kernel(const float* __restrict__ logits,
                                                   int* __restrict__ tki,
                                                   float* __restrict__ tkv,
                                                   float* __restrict__ logZ) {
  int t = blockIdx.x;
  const int tid = threadIdx.x;
  __shared__ unsigned skeys[2048];
  __shared__ unsigned hist[256];
  __shared__ unsigned suf[256];
  __shared__ float svals[512];
  __shared__ int s_want;
  __shared__ unsigned s_prefix;
  const float* row = logits + (long)t * 2048;
  for (int i = tid; i < 2048; i += 256) {
    unsigned u = __float_as_uint(row[i]);
    skeys[i] = (u & 0x80000000u) ? ~u : (u | 0x80000000u);
  }
  if (tid == 0) { s_want = 512; s_prefix = 0u; }
  __syncthreads();
  for (int shift = 24; shift >= 0; shift -= 8) {
    hist[tid] = 0u;
    __syncthreads();
    unsigned pmask = (shift == 24) ? 0u : (0xFFFFFFFFu << (shift + 8));
    unsigned pref = s_prefix;
    int want = s_want;
    for (int i = tid; i < 2048; i += 256) {
      unsigned k = skeys[i];
      if ((k & pmask) == pref) atomicAdd(&hist[(k >> shift) & 255u], 1u);
    }
    __syncthreads();
    // parallel inclusive suffix sum: suf[t] = sum_{b>=t} hist[b]
    suf[tid] = hist[tid];
    __syncthreads();
    #pragma unroll
    for (int d = 1; d < 256; d <<= 1) {
      unsigned v = suf[tid];
      unsigned add = (tid + d < 256) ? suf[tid + d] : 0u;
      __syncthreads();
      suf[tid] = v + add;
      __syncthreads();
    }
    unsigned Sb = suf[tid];
    unsigned Sb1 = (tid < 255) ? suf[tid + 1] : 0u;
    if ((int)Sb >= want && (int)Sb1 < want) {
      s_want = want - (int)Sb1;
      s_prefix = pref | ((unsigned)tid << shift);
    }
    __syncthreads();
  }
  unsigned T = s_prefix;
  int want_eq = s_want;
  int c_gt = 512 - want_eq;
  if (tid < 64) {
    int n_gt = 0, n_eq = 0;
    unsigned long long below = (1ull << tid) - 1ull;
    for (int base = 0; base < 2048; base += 64) {
      int i = base + (int)tid;
      unsigned k = skeys[i];
      bool gt = (k > T), eq = (k == T);
      unsigned long long bg = __ballot(gt);
      unsigned long long be = __ballot(eq);
      int slot = -1;
      if (gt) slot = n_gt + (int)__popcll(bg & below);
      else if (eq) {
        int er = n_eq + (int)__popcll(be & below);
        if (er < want_eq) slot = c_gt + er;
      }
      if (slot >= 0) {
        unsigned bits = (k & 0x80000000u) ? (k ^ 0x80000000u) : ~k;
        float val = __uint_as_float(bits);
        tki[(long)t * 512 + slot] = i;
        tkv[(long)t * 512 + slot] = val;
        svals[slot] = val;
      }
      n_gt += (int)__popcll(bg);
      n_eq += (int)__popcll(be);
    }
  }
  __syncthreads();
  float m = -3.4e38f;
  for (int i = tid; i < 512; i += 256) m = fmaxf(m, svals[i]);
  m = block_reduce_op(m, 1);
  float se = 0.f;
  for (int i = tid; i < 512; i += 256) se += expf(svals[i] - m);
  se = block_reduce_op(se, 0);
  if (tid == 0) logZ[t] = m + logf(se);
}

// ---------------- attn phase 1: QK^T + softmax + KL + dense-P emit ----------------
// 1 query/block, 4 waves. Q staged in LDS (padded stride 584); K gathered with
// prefetch-1. ph emit buffer aliases the q LDS region (dead after QK).
__global__ __launch_bounds__(256, 4) void attn_qk(
    const bf16* __restrict__ qabs, const bf16* __restrict__ keys,
    const int* __restrict__ tki, const float* __restrict__ tkv,
    const float* __restrict__ logZ, bf16* __restrict__ Pg,
    float* __restrict__ kl) {
  const int s = 2047 - blockIdx.x;  // heavy-first
  const int tid = threadIdx.x;
  const int wave = tid >> 6, lane = tid & 63, g = lane >> 4, li = lane & 15;
  __shared__ int idxs[512];
  __shared__ __align__(16) bf16 un[16 * 584];   // qs (16x584) then ph (16x512)
  __shared__ float red[64];
  __shared__ float mxf[16], dnf[16];
  bf16* qs = un;
  bf16* ph = un;

  for (int i = tid; i < 512; i += 256) idxs[i] = tki[(long)s * 512 + i];
  // stage q rows: 16 x 576, padded LDS stride 584 (2-way-free ds_read)
  for (int i = tid; i < 1152; i += 256) {
    int row = i / 72, c8 = i % 72;
    short8v v = *(const short8v*)(qabs + (long)s * 9216 + row * 576 + c8 * 8);
    *(short8v*)&qs[row * 584 + c8 * 8] = v;
  }
  __syncthreads();

  // ---- QK^T: A-frags from LDS, gathered B with prefetch-1 ----
  f32x4 accS[8];
  int kid[8];
  const bf16* kr[8];
  #pragma unroll
  for (int j = 0; j < 8; j++) {
    accS[j] = (f32x4){0.f,0.f,0.f,0.f};
    kid[j] = idxs[(wave * 8 + j) * 16 + li];
    kr[j] = keys + (long)kid[j] * 576 + g * 8;
  }
  short8v af = *(const short8v*)&qs[li * 584 + g * 8];
  short8v kf[8];
  #pragma unroll
  for (int j = 0; j < 8; j++) kf[j] = *(const short8v*)kr[j];
  for (int ks = 0; ks < 18; ks++) {
    const int nko = (ks < 17 ? ks + 1 : 17) * 32;
    short8v afn = *(const short8v*)&qs[li * 584 + nko + g * 8];
    short8v nx[8];
    #pragma unroll
    for (int j = 0; j < 8; j++) nx[j] = *(const short8v*)(kr[j] + nko);
    #pragma unroll
    for (int j = 0; j < 8; j++) accS[j] = MFMA16(af, kf[j], accS[j]);
    af = afn;
    #pragma unroll
    for (int j = 0; j < 8; j++) kf[j] = nx[j];
  }

  // ---- scale + mask + softmax ----
  float e[8][4];
  float m4[4];
  #pragma unroll
  for (int r = 0; r < 4; r++) m4[r] = -3.4e38f;
  #pragma unroll
  for (int j = 0; j < 8; j++) {
    float mask = (kid[j] <= s) ? 0.f : NEG_;
    #pragma unroll
    for (int r = 0; r < 4; r++) {
      e[j][r] = accS[j][r] * SCALE_ + mask;
      m4[r] = fmaxf(m4[r], e[j][r]);
    }
  }
  #pragma unroll
  for (int d = 1; d < 16; d <<= 1)
    #pragma unroll
    for (int r = 0; r < 4; r++) m4[r] = fmaxf(m4[r], __shfl_xor(m4[r], d));
  if (li == 0)
    #pragma unroll
    for (int r = 0; r < 4; r++) red[wave * 16 + g * 4 + r] = m4[r];
  __syncthreads();
  if (tid < 16) mxf[tid] = fmaxf(fmaxf(red[tid], red[16 + tid]), fmaxf(red[32 + tid], red[48 + tid]));
  __syncthreads();
  float d4[4] = {0.f, 0.f, 0.f, 0.f};
  #pragma unroll
  for (int j = 0; j < 8; j++)
    #pragma unroll
    for (int r = 0; r < 4; r++) {
      e[j][r] = __expf(e[j][r] - mxf[g * 4 + r]);
      d4[r] += e[j][r];
    }
  #pragma unroll
  for (int d = 1; d < 16; d <<= 1)
    #pragma unroll
    for (int r = 0; r < 4; r++) d4[r] += __shfl_xor(d4[r], d);
  if (li == 0)
    #pragma unroll
    for (int r = 0; r < 4; r++) red[wave * 16 + g * 4 + r] = d4[r];
  __syncthreads();
  if (tid < 16) dnf[tid] = red[tid] + red[16 + tid] + red[32 + tid] + red[48 + tid];
  __syncthreads();

  float invd[4];
  #pragma unroll
  for (int r = 0; r < 4; r++) invd[r] = 1.f / dnf[g * 4 + r];

  // ---- tas + KL ----
  float tasj[8];
  #pragma unroll
  for (int j = 0; j < 8; j++) {
    float t = 0.f;
    #pragma unroll
    for (int r = 0; r < 4; r++) t += e[j][r] * invd[r];
    t += __shfl_xor(t, 16);
    t += __shfl_xor(t, 32);
    tasj[j] = t;
  }
  float klacc = 0.f;
  if (g == 0) {
    float lz = logZ[s];
    #pragma unroll
    for (int j = 0; j < 8; j++) {
      int slot = (wave * 8 + j) * 16 + li;
      float tgt = fminf(fmaxf(logf(tasj[j] * 0.0625f), -100.f), 0.f);
      float inp = fminf(fmaxf(tkv[(long)s * 512 + slot] - lz, -100.f), 0.f);
      klacc += expf(tgt) * (tgt - inp);
    }
  }
  #pragma unroll
  for (int d = 1; d < 16; d <<= 1) klacc += __shfl_xor(klacc, d);
  if (lane == 0) atomicAdd(kl, klacc);

  // ---- emit dense normalized P rows (chunked via LDS, ph aliases qs) ----
  const int m = s >> 7;
  const int Km = (m + 1) << 7;
  const int rr = s & 127;
  bf16* Pbase = Pg + 131072L * m * (m + 1);
  for (int base = 0; base < Km; base += 512) {
    const int cw = min(512, Km - base);
    __syncthreads();
    { uint4 z = {0,0,0,0};
      for (int i = tid; i < 1024; i += 256) ((uint4*)ph)[i] = z; }
    __syncthreads();
    #pragma unroll
    for (int j = 0; j < 8; j++) {
      int kk = kid[j] - base;
      if (0 <= kk && kk < 512) {
        #pragma unroll
        for (int r = 0; r < 4; r++)
          ph[(g * 4 + r) * 512 + kk] = __float2bfloat16(e[j][r] * invd[r]);
      }
    }
    __syncthreads();
    for (int u = tid; u < 1024; u += 256) {
      int h = u >> 6, c = (u & 63) * 8;
      if (c < cw)
        *(short8v*)(Pbase + ((long)(h * 128 + rr) * Km + base + c)) =
            *(const short8v*)&ph[h * 512 + c];
    }
  }
}

// ---------------- attn phase 2: dense PV GEMM (triangular-packed P) ----------------
// grid (4 n-tiles, 16 m, 16 h). out aoc[s][h*512+d] bf16.
__global__ __launch_bounds__(256) void attn_pv(const bf16* __restrict__ Pg,
                                               const bf16* __restrict__ keys,
                                               bf16* __restrict__ aoc) {
  const int m = 15 - blockIdx.y;  // heavy-first
  const int h = blockIdx.z;
  const int Km = (m + 1) << 7;
  const bf16* A = Pg + 131072L * m * (m + 1) + (long)h * 128 * Km;
  const int n0 = blockIdx.x * 128;
  __shared__ bf16 As[4096];
  __shared__ bf16 Bs[4096];
  const int tid = threadIdx.x;
  const int wave = tid >> 6, lane = tid & 63, g = lane >> 4, li = lane & 15;
  const int mB = (wave >> 1) * 64, nB = (wave & 1) * 64;
  f32x4 acc[4][4];
  #pragma unroll
  for (int i = 0; i < 4; i++)
    #pragma unroll
    for (int j = 0; j < 4; j++) acc[i][j] = (f32x4){0.f, 0.f, 0.f, 0.f};

  for (int k0 = 0; k0 < Km; k0 += 32) {
    #pragma unroll
    for (int r2 = 0; r2 < 2; r2++) {
      int idx = r2 * 256 + tid;
      int row = idx >> 2, ko = (idx & 3) * 8;
      gld16(A + (long)row * Km + k0 + ko, &As[idx * 8]);
    }
    {
      int k = tid >> 3, nb = (tid & 7) * 16;
      const bf16* src = keys + (long)(k0 + k) * 576 + n0 + nb;
      short8v v0 = *(const short8v*)src;
      short8v v1 = *(const short8v*)(src + 8);
      #pragma unroll
      for (int j = 0; j < 8; j++) {
        Bs[(nb + j) * 32 + k]     = ((const bf16*)&v0)[j];
        Bs[(nb + 8 + j) * 32 + k] = ((const bf16*)&v1)[j];
      }
    }
    __syncthreads();
    short8v af[4], bfr[4];
    #pragma unroll
    for (int mt = 0; mt < 4; mt++) af[mt]  = *(const short8v*)&As[(mB + mt*16 + li) * 32 + g*8];
    #pragma unroll
    for (int nt = 0; nt < 4; nt++) bfr[nt] = *(const short8v*)&Bs[(nB + nt*16 + li) * 32 + g*8];
    #pragma unroll
    for (int mt = 0; mt < 4; mt++)
      #pragma unroll
      for (int nt = 0; nt < 4; nt++)
        acc[mt][nt] = MFMA16(af[mt], bfr[nt], acc[mt][nt]);
    __syncthreads();
  }
  #pragma unroll
  for (int mt = 0; mt < 4; mt++)
    #pragma unroll
    for (int nt = 0; nt < 4; nt++)
      #pragma unroll
      for (int r = 0; r < 4; r++) {
        int row = m * 128 + mB + mt*16 + g*4 + r;
        int col = n0 + nB + nt*16 + li;
        aoc[(long)row * 8192 + h * 512 + col] = __float2bfloat16(acc[mt][nt][r]);
      }
}

__global__ void zero_kernel(float* p) {
  if (threadIdx.x == 0 && blockIdx.x == 0) p[0] = 0.f;
}
__global__ void copykl_kernel(const float* src, float* dst) { dst[0] = src[0]; }

// ---------------- launch ----------------
extern "C" void kernel_launch(void* const* d_in, const int* in_sizes, int n_in,
                              void* d_out, int out_size, void* d_ws, size_t ws_size,
                              hipStream_t stream) {
  (void)in_sizes; (void)n_in; (void)out_size; (void)ws_size;
  const float* x        = (const float*)d_in[0];
  const float* wq_down  = (const float*)d_in[2];
  const float* q_ln_w   = (const float*)d_in[3];
  const float* wq_up    = (const float*)d_in[4];
  const float* wkv_down = (const float*)d_in[5];
  const float* kv_ln_w  = (const float*)d_in[6];
  const float* wk_up    = (const float*)d_in[7];
  const float* wv_up    = (const float*)d_in[8];
  const float* wo       = (const float*)d_in[9];
  const float* idx_wq_b = (const float*)d_in[10];
  const float* idx_wk   = (const float*)d_in[11];
  const float* idx_kn_w = (const float*)d_in[12];
  const float* idx_kn_b = (const float*)d_in[13];
  const float* idx_ww   = (const float*)d_in[14];
  float* out = (float*)d_out;

  char* w = (char*)d_ws;
  size_t off = 0;
  auto alloc = [&](size_t bytes) { void* p = w + off; off += (bytes + 255) & ~255ul; return p; };
  // ---- persistent (live across attention) ----
  bf16* keys_b  = (bf16*)alloc(2048L*576*2);
  bf16* qabs_b  = (bf16*)alloc(2048L*9216*2);
  bf16* aoc_b   = (bf16*)alloc(2048L*8192*2);
  bf16* ao_b    = (bf16*)alloc(2048L*2048*2);
  bf16* wvu_b   = (bf16*)alloc(16L*128*512*2);
  bf16* wo_b    = (bf16*)alloc(2048L*2048*2);
  float* tkv    = (float*)alloc(2048L*512*4);
  float* logZ   = (float*)alloc(2048*4);
  float* klbuf  = (float*)alloc(64);
  int*   tki    = (int*)alloc(2048L*512*4);
  // ---- scratch region (dead before attn_qk); Pg aliases it ----
  size_t scratch0 = off;
  bf16* Pg = (bf16*)(w + scratch0);  // triangular-packed, reuses scratch
  float* qr     = (float*)alloc(2048L*1536*4);
  float* kvtmp  = (float*)alloc(2048L*576*4);
  float* kitmp  = (float*)alloc(2048L*128*4);
  float* logits = (float*)alloc(2048L*2048*4);
  float* wgt    = (float*)alloc(2048L*4*4);
  bf16* x_b     = (bf16*)alloc(2048L*2048*2);
  bf16* qr_b    = (bf16*)alloc(2048L*1536*2);
  bf16* q_b     = (bf16*)alloc(2048L*3072*2);
  bf16* qi_b    = (bf16*)alloc(2048L*512*2);
  bf16* ki_b    = (bf16*)alloc(2048L*128*2);
  bf16* wqd_b   = (bf16*)alloc(1536L*2048*2);
  bf16* wqu_b   = (bf16*)alloc(3072L*1536*2);
  bf16* wkv_b   = (bf16*)alloc(576L*2048*2);
  bf16* wku_b   = (bf16*)alloc(16L*128*512*2);
  bf16* iwq_b   = (bf16*)alloc(512L*1536*2);
  bf16* iwk_b   = (bf16*)alloc(128L*2048*2);
  // ensure scratch covers Pg
  size_t pg_end = scratch0 + 131072ul*16*17*2;
  if (off < pg_end) off = pg_end;

  dim3 b256(256);
  CvtArgs ca;
  ca.seg[0] = { x,        x_b,   2048L*2048 };
  ca.seg[1] = { wq_down,  wqd_b, 1536L*2048 };
  ca.seg[2] = { wq_up,    wqu_b, 3072L*1536 };
  ca.seg[3] = { wkv_down, wkv_b, 576L*2048 };
  ca.seg[4] = { wk_up,    wku_b, 16L*128*512 };
  ca.seg[5] = { wv_up,    wvu_b, 16L*128*512 };
  ca.seg[6] = { wo,       wo_b,  2048L*2048 };
  ca.seg[7] = { idx_wq_b, iwq_b, 512L*1536 };
  ca.seg[8] = { idx_wk,   iwk_b, 128L*2048 };
  f2b_multi<<<2048, b256, 0, stream>>>(ca);

  // qr = x @ wq_down^T (f32 out), rmsnorm -> qr_b
  gemm_bf16<1,0><<<dim3(12,16), b256, 0, stream>>>(x_b, wqd_b, qr, 2048,1536,2048, 2048,2048,1536, 0,0,0);
  rmsnorm_b_kernel<<<2048, b256, 0, stream>>>(qr, q_ln_w, qr_b, 1536);
  // q = qr @ wq_up^T (bf16 out)
  gemm_bf16<1,1><<<dim3(24,16), b256, 0, stream>>>(qr_b, wqu_b, q_b, 2048,3072,1536, 1536,1536,3072, 0,0,0);
  // kv = x @ wkv_down^T (f32), norm+rope -> keys_b
  gemm_bf16<1,0><<<dim3(5,16), b256, 0, stream>>>(x_b, wkv_b, kvtmp, 2048,576,2048, 2048,2048,576, 0,0,0);
  kv_norm_rope_kernel<<<2048, b256, 0, stream>>>(kvtmp, kv_ln_w, keys_b);
  // qabs: pe rope + nope batched GEMM
  rope_q_kernel<<<4096, b256, 0, stream>>>(q_b, qabs_b);
  gemm_bf16<0,1><<<dim3(4,16,16), b256, 0, stream>>>(q_b, wku_b, qabs_b, 2048,512,128, 3072,512,9216, 192, 128L*512, 576);
  // indexer q
  gemm_bf16<1,1><<<dim3(4,16), b256, 0, stream>>>(qr_b, iwq_b, qi_b, 2048,512,1536, 1536,1536,512, 0,0,0);
  rope_qi_kernel<<<1024, b256, 0, stream>>>(qi_b);
  // indexer k
  gemm_bf16<1,0><<<dim3(1,16), b256, 0, stream>>>(x_b, iwk_b, kitmp, 2048,128,2048, 2048,2048,128, 0,0,0);
  ki_ln_rope_kernel<<<2048, dim3(128), 0, stream>>>(kitmp, idx_kn_w, idx_kn_b, ki_b);
  wgt_kernel<<<2048, b256, 0, stream>>>(x, idx_ww, wgt);
  // logits + topk
  idx_logits_mfma<<<dim3(16,32), b256, 0, stream>>>(qi_b, ki_b, wgt, logits);
  topk_kernel<<<2048, b256, 0, stream>>>(logits, tki, tkv, logZ);
  // attention (split)
  zero_kernel<<<1, 64, 0, stream>>>(klbuf);
  attn_qk<<<2048, b256, 0, stream>>>(qabs_b, keys_b, tki, tkv, logZ, Pg, klbuf);
  attn_pv<<<dim3(4,16,16), b256, 0, stream>>>(Pg, keys_b, aoc_b);
  // v_up (batched) and output projection
  gemm_bf16<1,1><<<dim3(1,16,16), b256, 0, stream>>>(aoc_b, wvu_b, ao_b, 2048,128,512, 8192,512,2048, 512, 128L*512, 128);
  gemm_bf16<1,0><<<dim3(16,16), b256, 0, stream>>>(ao_b, wo_b, out, 2048,2048,2048, 2048,2048,2048, 0,0,0);
  copykl_kernel<<<1, 1, 0, stream>>>(klbuf, out + 4194304L);
}